// Round 1
// baseline (406.180 us; speedup 1.0000x reference)
//
#include <hip/hip_runtime.h>
#include <hip/hip_bf16.h>

// MultiHeadSelfAttention on MI355X (gfx950), bf16 MFMA pipeline.
// Workspace layout (needs 56 MB):
//   [ 0MB) xb   : x as bf16            (4096x1024)
//   [ 8MB) Wt   : Wq^T|Wk^T|Wv^T|Wo^T  (4 x 1024x1024 bf16)
//   [16MB) Qb   : Q (pre-scaled 0.125) (4096x1024 bf16)
//   [24MB) Kb   : K                    (4096x1024 bf16)
//   [32MB) Vb   : V                    (4096x1024 bf16)
//   [40MB) Vt   : V^T per head         (2,16,64,2048 bf16)
//   [48MB) Ctx  : attention output     (4096x1024 bf16)

using bf16 = __hip_bfloat16;
typedef __attribute__((ext_vector_type(8))) short bf16x8_t;
typedef __attribute__((ext_vector_type(4))) float f32x4_t;

#define MFMA(a, b, c) __builtin_amdgcn_mfma_f32_16x16x32_bf16((a), (b), (c), 0, 0, 0)

constexpr int SEQ = 2048;
constexpr int DIM = 1024;
constexpr int HD  = 64;
constexpr int MROWS = 2 * SEQ;  // 4096

// ---------------- convert x: fp32 -> bf16, 4 elems/thread ----------------
__global__ __launch_bounds__(256) void k_convert_x(const float4* __restrict__ x,
                                                   ushort4* __restrict__ xb) {
    int i = blockIdx.x * 256 + threadIdx.x;
    float4 v = x[i];
    ushort4 o;
    o.x = __builtin_bit_cast(unsigned short, __float2bfloat16(v.x));
    o.y = __builtin_bit_cast(unsigned short, __float2bfloat16(v.y));
    o.z = __builtin_bit_cast(unsigned short, __float2bfloat16(v.z));
    o.w = __builtin_bit_cast(unsigned short, __float2bfloat16(v.w));
    xb[i] = o;
}

// -------- transpose+convert weights: W (k,n) fp32 -> Wt (n,k) bf16 --------
__global__ __launch_bounds__(256) void k_transpose_w(const float* __restrict__ W0,
                                                     const float* __restrict__ W1,
                                                     const float* __restrict__ W2,
                                                     const float* __restrict__ W3,
                                                     bf16* __restrict__ Wt) {
    const float* W = blockIdx.z == 0 ? W0 : blockIdx.z == 1 ? W1
                   : blockIdx.z == 2 ? W2 : W3;
    bf16* out = Wt + (size_t)blockIdx.z * DIM * DIM;
    __shared__ float tile[64][65];
    int r0 = blockIdx.x * 64, c0 = blockIdx.y * 64;
    int t = threadIdx.x;
    int c = t & 63, rq = t >> 6;
#pragma unroll
    for (int j = 0; j < 16; ++j) {
        int r = rq + j * 4;
        tile[r][c] = W[(size_t)(r0 + r) * DIM + c0 + c];
    }
    __syncthreads();
#pragma unroll
    for (int j = 0; j < 16; ++j) {
        int n = rq + j * 4;
        out[(size_t)(c0 + n) * DIM + r0 + c] = __float2bfloat16(tile[c][n]);
    }
}

// ---------------- fused QKV GEMM: 128x128 tile, 4 waves ----------------
// A (4096,1024) bf16; Bt = Wq^T|Wk^T|Wv^T (3072,1024); Out = Q|K|V contiguous.
__global__ __launch_bounds__(256) void k_gemm_qkv(const bf16* __restrict__ A,
                                                  const bf16* __restrict__ Bt,
                                                  const float* __restrict__ bq,
                                                  const float* __restrict__ bk,
                                                  const float* __restrict__ bv,
                                                  bf16* __restrict__ Out) {
    constexpr int K = DIM;
    __shared__ bf16 As[128 * 32];
    __shared__ bf16 Bs[128 * 32];
    int t = threadIdx.x;
    int l = t & 63;
    int w = t >> 6;
    int lr = l & 15, lg = l >> 4;
    int wr = w >> 1, wc = w & 1;
    int m0 = blockIdx.x * 128;
    int n0 = blockIdx.y * 128;

    f32x4_t acc[4][4] = {};

    int sr = t >> 2;           // staging row 0..63
    int sc = (t & 3) * 8;      // staging col chunk
    const bf16* ga = A + (size_t)(m0 + sr) * K + sc;
    const bf16* gb = Bt + (size_t)(n0 + sr) * K + sc;
    char* wa = (char*)As + t * 16;
    char* wb = (char*)Bs + t * 16;

    for (int k0 = 0; k0 < K; k0 += 32) {
        bf16x8_t va0 = *(const bf16x8_t*)ga;
        bf16x8_t va1 = *(const bf16x8_t*)(ga + (size_t)64 * K);
        bf16x8_t vb0 = *(const bf16x8_t*)gb;
        bf16x8_t vb1 = *(const bf16x8_t*)(gb + (size_t)64 * K);
        ga += 32; gb += 32;
        *(bf16x8_t*)wa = va0;
        *(bf16x8_t*)(wa + 4096) = va1;
        *(bf16x8_t*)wb = vb0;
        *(bf16x8_t*)(wb + 4096) = vb1;
        __syncthreads();
        bf16x8_t af[4], bfv[4];
#pragma unroll
        for (int mi = 0; mi < 4; ++mi)
            af[mi] = *(const bf16x8_t*)&As[(wr * 64 + mi * 16 + lr) * 32 + lg * 8];
#pragma unroll
        for (int ni = 0; ni < 4; ++ni)
            bfv[ni] = *(const bf16x8_t*)&Bs[(wc * 64 + ni * 16 + lr) * 32 + lg * 8];
#pragma unroll
        for (int mi = 0; mi < 4; ++mi)
#pragma unroll
            for (int ni = 0; ni < 4; ++ni)
                acc[mi][ni] = MFMA(af[mi], bfv[ni], acc[mi][ni]);
        __syncthreads();
    }

    int seg = n0 >> 10;  // 0=Q 1=K 2=V
    int nl = (n0 & 1023) + wc * 64;
    const float* bias = seg == 0 ? bq : seg == 1 ? bk : bv;
    float alpha = seg == 0 ? 0.125f : 1.0f;  // fold 1/sqrt(hd) into Q
    bf16* outp = Out + (size_t)seg * MROWS * DIM;
#pragma unroll
    for (int mi = 0; mi < 4; ++mi) {
#pragma unroll
        for (int ni = 0; ni < 4; ++ni) {
            int row = m0 + wr * 64 + mi * 16 + lg * 4;
            int col = nl + ni * 16 + lr;
            float bb = bias[col];
#pragma unroll
            for (int r = 0; r < 4; ++r) {
                float v = (acc[mi][ni][r] + bb) * alpha;
                outp[(size_t)(row + r) * DIM + col] = __float2bfloat16(v);
            }
        }
    }
}

// ------------- transpose V: (4096,1024) -> Vt (2,16,64,2048) -------------
__global__ __launch_bounds__(256) void k_transpose_v(const bf16* __restrict__ Vb,
                                                     bf16* __restrict__ Vt) {
    int s0 = blockIdx.x * 64;
    int bh = blockIdx.y;
    int b = bh >> 4, h = bh & 15;
    __shared__ bf16 tile[64][66];
    int t = threadIdx.x;
    int c = t & 63, rq = t >> 6;
#pragma unroll
    for (int j = 0; j < 16; ++j) {
        int s = rq + j * 4;
        tile[s][c] = Vb[(size_t)(b * SEQ + s0 + s) * DIM + h * HD + c];
    }
    __syncthreads();
#pragma unroll
    for (int j = 0; j < 16; ++j) {
        int d = rq + j * 4;
        Vt[((size_t)bh * HD + d) * SEQ + s0 + c] = tile[c][d];
    }
}

// ---------------- flash attention: 64 q-rows/block, 4 waves ----------------
__global__ __launch_bounds__(256) void k_attn(const bf16* __restrict__ Qb,
                                              const bf16* __restrict__ Kb,
                                              const bf16* __restrict__ Vt,
                                              const int* __restrict__ amask,
                                              bf16* __restrict__ Ctx) {
    int qt = blockIdx.x;   // q tile of 64
    int bh = blockIdx.y;
    int b = bh >> 4, h = bh & 15;
    int t = threadIdx.x;
    int w = t >> 6, l = t & 63;
    int lr = l & 15, lg = l >> 4;
    int m0 = qt * 64 + w * 16;  // this wave's q rows (within seq)

    __shared__ bf16 Pl[4][16 * 72];  // per-wave P scratch, padded rows (36 dwords)
    bf16* pl = &Pl[w][0];

    // Q fragments (Q pre-scaled by 0.125), kept in registers
    const bf16* qbase = Qb + (size_t)(b * SEQ + m0 + lr) * DIM + h * HD;
    bf16x8_t qf[2];
#pragma unroll
    for (int ks = 0; ks < 2; ++ks)
        qf[ks] = *(const bf16x8_t*)(qbase + ks * 32 + lg * 8);

    f32x4_t o[4] = {};
    float mrow[4], lrow[4];
#pragma unroll
    for (int r = 0; r < 4; ++r) { mrow[r] = -1e30f; lrow[r] = 0.f; }

    const bf16* vtb = Vt + (size_t)bh * HD * SEQ;

    for (int kt = 0; kt <= qt; ++kt) {
        // ---- scores S = Q K^T (already scaled) ----
        f32x4_t s[4];
#pragma unroll
        for (int ni = 0; ni < 4; ++ni) {
            f32x4_t a = {0.f, 0.f, 0.f, 0.f};
            const bf16* kb = Kb + (size_t)(b * SEQ + kt * 64 + ni * 16 + lr) * DIM + h * HD;
#pragma unroll
            for (int ks = 0; ks < 2; ++ks) {
                bf16x8_t kf = *(const bf16x8_t*)(kb + ks * 32 + lg * 8);
                a = MFMA(qf[ks], kf, a);
            }
            s[ni] = a;
        }
        // ---- causal + padding mask (set to -1e30, matching reference) ----
#pragma unroll
        for (int ni = 0; ni < 4; ++ni) {
            int key = kt * 64 + ni * 16 + lr;
            bool kv = amask[b * SEQ + key] > 0;
#pragma unroll
            for (int r = 0; r < 4; ++r) {
                int qrow = m0 + lg * 4 + r;
                if (!kv || key > qrow) s[ni][r] = -1e30f;
            }
        }
        // ---- online softmax: row stats via 16-lane shfl reductions ----
        float tm[4];
#pragma unroll
        for (int r = 0; r < 4; ++r) {
            tm[r] = fmaxf(fmaxf(s[0][r], s[1][r]), fmaxf(s[2][r], s[3][r]));
            tm[r] = fmaxf(tm[r], __shfl_xor(tm[r], 1));
            tm[r] = fmaxf(tm[r], __shfl_xor(tm[r], 2));
            tm[r] = fmaxf(tm[r], __shfl_xor(tm[r], 4));
            tm[r] = fmaxf(tm[r], __shfl_xor(tm[r], 8));
        }
        float rs[4];
#pragma unroll
        for (int r = 0; r < 4; ++r) {
            float mnew = fmaxf(mrow[r], tm[r]);
            float al = __expf(mrow[r] - mnew);
            mrow[r] = mnew;
            lrow[r] *= al;
            rs[r] = 0.f;
#pragma unroll
            for (int ni = 0; ni < 4; ++ni) {
                float p = __expf(s[ni][r] - mnew);
                s[ni][r] = p;
                rs[r] += p;
            }
#pragma unroll
            for (int ni = 0; ni < 4; ++ni)
                o[ni][r] *= al;
        }
#pragma unroll
        for (int r = 0; r < 4; ++r) {
            rs[r] += __shfl_xor(rs[r], 1);
            rs[r] += __shfl_xor(rs[r], 2);
            rs[r] += __shfl_xor(rs[r], 4);
            rs[r] += __shfl_xor(rs[r], 8);
            lrow[r] += rs[r];
        }
        // ---- P (C-layout) -> LDS -> A-layout for PV ----
#pragma unroll
        for (int ni = 0; ni < 4; ++ni)
#pragma unroll
            for (int r = 0; r < 4; ++r)
                pl[(lg * 4 + r) * 72 + ni * 16 + lr] = __float2bfloat16(s[ni][r]);
        __syncthreads();
        const bf16* vk = vtb + kt * 64;
#pragma unroll
        for (int ks = 0; ks < 2; ++ks) {
            bf16x8_t pf = *(const bf16x8_t*)&pl[lr * 72 + ks * 32 + lg * 8];
#pragma unroll
            for (int ni = 0; ni < 4; ++ni) {
                bf16x8_t vf = *(const bf16x8_t*)(vk + (size_t)(ni * 16 + lr) * SEQ + ks * 32 + lg * 8);
                o[ni] = MFMA(pf, vf, o[ni]);
            }
        }
        __syncthreads();
    }

    // ---- normalize and write ctx (bf16, natural (4096,1024) layout) ----
#pragma unroll
    for (int r = 0; r < 4; ++r) {
        float inv = 1.0f / lrow[r];
        int row = b * SEQ + m0 + lg * 4 + r;
#pragma unroll
        for (int ni = 0; ni < 4; ++ni)
            Ctx[(size_t)row * DIM + h * HD + ni * 16 + lr] =
                __float2bfloat16(o[ni][r] * inv);
    }
}

// ---------------- output projection GEMM -> fp32 d_out ----------------
__global__ __launch_bounds__(256) void k_gemm_out(const bf16* __restrict__ A,
                                                  const bf16* __restrict__ Bt,
                                                  const float* __restrict__ bias,
                                                  float* __restrict__ Out) {
    constexpr int K = DIM;
    __shared__ bf16 As[128 * 32];
    __shared__ bf16 Bs[128 * 32];
    int t = threadIdx.x;
    int l = t & 63;
    int w = t >> 6;
    int lr = l & 15, lg = l >> 4;
    int wr = w >> 1, wc = w & 1;
    int m0 = blockIdx.x * 128;
    int n0 = blockIdx.y * 128;

    f32x4_t acc[4][4] = {};

    int sr = t >> 2;
    int sc = (t & 3) * 8;
    const bf16* ga = A + (size_t)(m0 + sr) * K + sc;
    const bf16* gb = Bt + (size_t)(n0 + sr) * K + sc;
    char* wa = (char*)As + t * 16;
    char* wb = (char*)Bs + t * 16;

    for (int k0 = 0; k0 < K; k0 += 32) {
        bf16x8_t va0 = *(const bf16x8_t*)ga;
        bf16x8_t va1 = *(const bf16x8_t*)(ga + (size_t)64 * K);
        bf16x8_t vb0 = *(const bf16x8_t*)gb;
        bf16x8_t vb1 = *(const bf16x8_t*)(gb + (size_t)64 * K);
        ga += 32; gb += 32;
        *(bf16x8_t*)wa = va0;
        *(bf16x8_t*)(wa + 4096) = va1;
        *(bf16x8_t*)wb = vb0;
        *(bf16x8_t*)(wb + 4096) = vb1;
        __syncthreads();
        bf16x8_t af[4], bfv[4];
#pragma unroll
        for (int mi = 0; mi < 4; ++mi)
            af[mi] = *(const bf16x8_t*)&As[(wr * 64 + mi * 16 + lr) * 32 + lg * 8];
#pragma unroll
        for (int ni = 0; ni < 4; ++ni)
            bfv[ni] = *(const bf16x8_t*)&Bs[(wc * 64 + ni * 16 + lr) * 32 + lg * 8];
#pragma unroll
        for (int mi = 0; mi < 4; ++mi)
#pragma unroll
            for (int ni = 0; ni < 4; ++ni)
                acc[mi][ni] = MFMA(af[mi], bfv[ni], acc[mi][ni]);
        __syncthreads();
    }

    int nl = n0 + wc * 64;
#pragma unroll
    for (int mi = 0; mi < 4; ++mi) {
#pragma unroll
        for (int ni = 0; ni < 4; ++ni) {
            int row = m0 + wr * 64 + mi * 16 + lg * 4;
            int col = nl + ni * 16 + lr;
            float bb = bias[col];
#pragma unroll
            for (int r = 0; r < 4; ++r)
                Out[(size_t)(row + r) * DIM + col] = acc[mi][ni][r] + bb;
        }
    }
}

extern "C" void kernel_launch(void* const* d_in, const int* in_sizes, int n_in,
                              void* d_out, int out_size, void* d_ws, size_t ws_size,
                              hipStream_t stream) {
    const float* x  = (const float*)d_in[0];
    const int*   am = (const int*)d_in[1];
    const float* Wq = (const float*)d_in[2];
    const float* bq = (const float*)d_in[3];
    const float* Wk = (const float*)d_in[4];
    const float* bk = (const float*)d_in[5];
    const float* Wv = (const float*)d_in[6];
    const float* bv = (const float*)d_in[7];
    const float* Wo = (const float*)d_in[8];
    const float* bo = (const float*)d_in[9];

    char* ws = (char*)d_ws;
    const size_t MB = (size_t)1 << 20;
    bf16* xb  = (bf16*)(ws + 0 * MB);
    bf16* Wt  = (bf16*)(ws + 8 * MB);
    bf16* Qb  = (bf16*)(ws + 16 * MB);   // Q|K|V contiguous (24 MB)
    bf16* Vb  = (bf16*)(ws + 32 * MB);
    bf16* Vt  = (bf16*)(ws + 40 * MB);
    bf16* Ctx = (bf16*)(ws + 48 * MB);

    k_convert_x<<<dim3(MROWS * DIM / 4 / 256), 256, 0, stream>>>(
        (const float4*)x, (ushort4*)xb);
    k_transpose_w<<<dim3(16, 16, 4), 256, 0, stream>>>(Wq, Wk, Wv, Wo, Wt);
    k_gemm_qkv<<<dim3(32, 24), 256, 0, stream>>>(xb, Wt, bq, bk, bv, Qb);
    k_transpose_v<<<dim3(32, 32), 256, 0, stream>>>(Vb, Vt);
    k_attn<<<dim3(32, 32), 256, 0, stream>>>(Qb, Qb + (size_t)MROWS * DIM, Vt, am, Ctx);
    k_gemm_out<<<dim3(32, 8), 256, 0, stream>>>(Ctx, Wt + (size_t)3 * DIM * DIM, bo,
                                                (float*)d_out);
}

// Round 2
// 386.916 us; speedup vs baseline: 1.0498x; 1.0498x over previous
//
#include <hip/hip_runtime.h>
#include <hip/hip_bf16.h>

// MultiHeadSelfAttention on MI355X (gfx950), bf16 MFMA pipeline.
// Workspace layout (needs 56 MB):
//   [ 0MB) xb   : x as bf16            (4096x1024)
//   [ 8MB) Wt   : Wq^T|Wk^T|Wv^T|Wo^T  (4 x 1024x1024 bf16)
//   [16MB) Qb   : Q (pre-scaled 0.125) (4096x1024 bf16)
//   [24MB) Kb   : K                    (4096x1024 bf16)
//   [32MB) Vb   : V                    (4096x1024 bf16)
//   [40MB) Vt   : V^T per head         (2,16,64,2048 bf16)
//   [48MB) Ctx  : attention output     (4096x1024 bf16)

using bf16 = __hip_bfloat16;
typedef __attribute__((ext_vector_type(8))) short bf16x8_t;
typedef __attribute__((ext_vector_type(4))) float f32x4_t;

#define MFMA(a, b, c) __builtin_amdgcn_mfma_f32_16x16x32_bf16((a), (b), (c), 0, 0, 0)

constexpr int SEQ = 2048;
constexpr int DIM = 1024;
constexpr int HD  = 64;
constexpr int MROWS = 2 * SEQ;  // 4096

// async global->LDS, 16B per lane (m97 pattern). LDS dest must be
// wave-uniform base + lane*16 in lane order (m104) — our layouts are.
__device__ __forceinline__ void gload_lds16(const bf16* g, bf16* l) {
    __builtin_amdgcn_global_load_lds(
        (const __attribute__((address_space(1))) unsigned int*)g,
        (__attribute__((address_space(3))) unsigned int*)l, 16, 0, 0);
}

// ---------------- convert x: fp32 -> bf16, 4 elems/thread ----------------
__global__ __launch_bounds__(256) void k_convert_x(const float4* __restrict__ x,
                                                   ushort4* __restrict__ xb) {
    int i = blockIdx.x * 256 + threadIdx.x;
    float4 v = x[i];
    ushort4 o;
    o.x = __builtin_bit_cast(unsigned short, __float2bfloat16(v.x));
    o.y = __builtin_bit_cast(unsigned short, __float2bfloat16(v.y));
    o.z = __builtin_bit_cast(unsigned short, __float2bfloat16(v.z));
    o.w = __builtin_bit_cast(unsigned short, __float2bfloat16(v.w));
    xb[i] = o;
}

// -------- transpose+convert weights: W (k,n) fp32 -> Wt (n,k) bf16 --------
__global__ __launch_bounds__(256) void k_transpose_w(const float* __restrict__ W0,
                                                     const float* __restrict__ W1,
                                                     const float* __restrict__ W2,
                                                     const float* __restrict__ W3,
                                                     bf16* __restrict__ Wt) {
    const float* W = blockIdx.z == 0 ? W0 : blockIdx.z == 1 ? W1
                   : blockIdx.z == 2 ? W2 : W3;
    bf16* out = Wt + (size_t)blockIdx.z * DIM * DIM;
    __shared__ float tile[64][65];
    int r0 = blockIdx.x * 64, c0 = blockIdx.y * 64;
    int t = threadIdx.x;
    int c = t & 63, rq = t >> 6;
#pragma unroll
    for (int j = 0; j < 16; ++j) {
        int r = rq + j * 4;
        tile[r][c] = W[(size_t)(r0 + r) * DIM + c0 + c];
    }
    __syncthreads();
#pragma unroll
    for (int j = 0; j < 16; ++j) {
        int n = rq + j * 4;
        out[(size_t)(c0 + n) * DIM + r0 + c] = __float2bfloat16(tile[c][n]);
    }
}

// ---------------- fused QKV GEMM: 128x128 tile, 4 waves ----------------
// A (4096,1024) bf16; Bt = Wq^T|Wk^T|Wv^T (3072,1024); Out = Q|K|V contiguous.
__global__ __launch_bounds__(256) void k_gemm_qkv(const bf16* __restrict__ A,
                                                  const bf16* __restrict__ Bt,
                                                  const float* __restrict__ bq,
                                                  const float* __restrict__ bk,
                                                  const float* __restrict__ bv,
                                                  bf16* __restrict__ Out) {
    constexpr int K = DIM;
    __shared__ bf16 As[128 * 32];
    __shared__ bf16 Bs[128 * 32];
    int t = threadIdx.x;
    int l = t & 63;
    int w = t >> 6;
    int lr = l & 15, lg = l >> 4;
    int wr = w >> 1, wc = w & 1;
    int m0 = blockIdx.x * 128;
    int n0 = blockIdx.y * 128;

    f32x4_t acc[4][4] = {};

    int sr = t >> 2;           // staging row 0..63
    int sc = (t & 3) * 8;      // staging col chunk
    const bf16* ga = A + (size_t)(m0 + sr) * K + sc;
    const bf16* gb = Bt + (size_t)(n0 + sr) * K + sc;
    bf16* wa = As + t * 8;     // lane-ordered contiguous 16B slots
    bf16* wb = Bs + t * 8;

    for (int k0 = 0; k0 < K; k0 += 32) {
        gload_lds16(ga, wa);
        gload_lds16(ga + (size_t)64 * K, wa + 2048);
        gload_lds16(gb, wb);
        gload_lds16(gb + (size_t)64 * K, wb + 2048);
        ga += 32; gb += 32;
        __syncthreads();   // drains vmcnt -> LDS tiles ready
        bf16x8_t af[4], bfv[4];
#pragma unroll
        for (int mi = 0; mi < 4; ++mi)
            af[mi] = *(const bf16x8_t*)&As[(wr * 64 + mi * 16 + lr) * 32 + lg * 8];
#pragma unroll
        for (int ni = 0; ni < 4; ++ni)
            bfv[ni] = *(const bf16x8_t*)&Bs[(wc * 64 + ni * 16 + lr) * 32 + lg * 8];
#pragma unroll
        for (int mi = 0; mi < 4; ++mi)
#pragma unroll
            for (int ni = 0; ni < 4; ++ni)
                acc[mi][ni] = MFMA(af[mi], bfv[ni], acc[mi][ni]);
        __syncthreads();
    }

    int seg = n0 >> 10;  // 0=Q 1=K 2=V
    int nl = (n0 & 1023) + wc * 64;
    const float* bias = seg == 0 ? bq : seg == 1 ? bk : bv;
    float alpha = seg == 0 ? 0.125f : 1.0f;  // fold 1/sqrt(hd) into Q
    bf16* outp = Out + (size_t)seg * MROWS * DIM;
#pragma unroll
    for (int mi = 0; mi < 4; ++mi) {
#pragma unroll
        for (int ni = 0; ni < 4; ++ni) {
            int row = m0 + wr * 64 + mi * 16 + lg * 4;
            int col = nl + ni * 16 + lr;
            float bb = bias[col];
#pragma unroll
            for (int r = 0; r < 4; ++r) {
                float v = (acc[mi][ni][r] + bb) * alpha;
                outp[(size_t)(row + r) * DIM + col] = __float2bfloat16(v);
            }
        }
    }
}

// ------------- transpose V: (4096,1024) -> Vt (2,16,64,2048) -------------
__global__ __launch_bounds__(256) void k_transpose_v(const bf16* __restrict__ Vb,
                                                     bf16* __restrict__ Vt) {
    int s0 = blockIdx.x * 64;
    int bh = blockIdx.y;
    int b = bh >> 4, h = bh & 15;
    __shared__ bf16 tile[64][66];
    int t = threadIdx.x;
    int c = t & 63, rq = t >> 6;
#pragma unroll
    for (int j = 0; j < 16; ++j) {
        int s = rq + j * 4;
        tile[s][c] = Vb[(size_t)(b * SEQ + s0 + s) * DIM + h * HD + c];
    }
    __syncthreads();
#pragma unroll
    for (int j = 0; j < 16; ++j) {
        int d = rq + j * 4;
        Vt[((size_t)bh * HD + d) * SEQ + s0 + c] = tile[c][d];
    }
}

// -------- flash attention: 64 q-rows/block, 4 independent waves --------
// KVBLK=128 (halves softmax rounds). No __syncthreads: P scratch is
// per-wave, double-buffered; per-wave lgkmcnt fence orders LDS write->read.
__global__ __launch_bounds__(256) void k_attn(const bf16* __restrict__ Qb,
                                              const bf16* __restrict__ Kb,
                                              const bf16* __restrict__ Vt,
                                              const int* __restrict__ amask,
                                              bf16* __restrict__ Ctx) {
    int qt = blockIdx.x;   // q tile of 64
    int bh = blockIdx.y;
    int b = bh >> 4, h = bh & 15;
    int t = threadIdx.x;
    int w = t >> 6, l = t & 63;
    int lr = l & 15, lg = l >> 4;
    int m0 = qt * 64 + w * 16;  // this wave's q rows (within seq)

    __shared__ bf16 Pl[4][2][16 * 136];  // per-wave, double-buffered

    // Q fragments (Q pre-scaled by 0.125), kept in registers
    const bf16* qbase = Qb + (size_t)(b * SEQ + m0 + lr) * DIM + h * HD;
    bf16x8_t qf[2];
#pragma unroll
    for (int ks = 0; ks < 2; ++ks)
        qf[ks] = *(const bf16x8_t*)(qbase + ks * 32 + lg * 8);

    f32x4_t o[4] = {};
    float mrow[4], lrow[4];
#pragma unroll
    for (int r = 0; r < 4; ++r) { mrow[r] = -1e30f; lrow[r] = 0.f; }

    const bf16* vtb = Vt + (size_t)bh * HD * SEQ;
    const bf16* kbb = Kb + (size_t)(b * SEQ + lr) * DIM + h * HD + lg * 8;

    int nkt = (qt >> 1) + 1;  // kv tiles of 128 keys
    for (int kt = 0; kt < nkt; ++kt) {
        // ---- scores S = Q K^T (already scaled), 128 keys ----
        f32x4_t s[8];
#pragma unroll
        for (int ni = 0; ni < 8; ++ni) {
            f32x4_t a = {0.f, 0.f, 0.f, 0.f};
            const bf16* kb = kbb + (size_t)(kt * 128 + ni * 16) * DIM;
#pragma unroll
            for (int ks = 0; ks < 2; ++ks) {
                bf16x8_t kf = *(const bf16x8_t*)(kb + ks * 32);
                a = MFMA(qf[ks], kf, a);
            }
            s[ni] = a;
        }
        // ---- causal + padding mask (set to -1e30, matching reference) ----
#pragma unroll
        for (int ni = 0; ni < 8; ++ni) {
            int key = kt * 128 + ni * 16 + lr;
            bool kv = amask[b * SEQ + key] > 0;
#pragma unroll
            for (int r = 0; r < 4; ++r) {
                int qrow = m0 + lg * 4 + r;
                if (!kv || key > qrow) s[ni][r] = -1e30f;
            }
        }
        // ---- online softmax: row stats via 16-lane shfl reductions ----
        float tm[4];
#pragma unroll
        for (int r = 0; r < 4; ++r) {
            float a0 = fmaxf(fmaxf(s[0][r], s[1][r]), fmaxf(s[2][r], s[3][r]));
            float a1 = fmaxf(fmaxf(s[4][r], s[5][r]), fmaxf(s[6][r], s[7][r]));
            tm[r] = fmaxf(a0, a1);
            tm[r] = fmaxf(tm[r], __shfl_xor(tm[r], 1));
            tm[r] = fmaxf(tm[r], __shfl_xor(tm[r], 2));
            tm[r] = fmaxf(tm[r], __shfl_xor(tm[r], 4));
            tm[r] = fmaxf(tm[r], __shfl_xor(tm[r], 8));
        }
        float rs[4];
#pragma unroll
        for (int r = 0; r < 4; ++r) {
            float mnew = fmaxf(mrow[r], tm[r]);
            float al = __expf(mrow[r] - mnew);
            mrow[r] = mnew;
            lrow[r] *= al;
            rs[r] = 0.f;
#pragma unroll
            for (int ni = 0; ni < 8; ++ni) {
                float p = __expf(s[ni][r] - mnew);
                s[ni][r] = p;
                rs[r] += p;
            }
#pragma unroll
            for (int ni = 0; ni < 4; ++ni)
                o[ni][r] *= al;
        }
#pragma unroll
        for (int r = 0; r < 4; ++r) {
            rs[r] += __shfl_xor(rs[r], 1);
            rs[r] += __shfl_xor(rs[r], 2);
            rs[r] += __shfl_xor(rs[r], 4);
            rs[r] += __shfl_xor(rs[r], 8);
            lrow[r] += rs[r];
        }
        // ---- P (C-layout) -> per-wave LDS -> A-layout for PV ----
        bf16* plw = &Pl[w][kt & 1][0];
        asm volatile("" ::: "memory");  // keep stores after prior reads
#pragma unroll
        for (int ni = 0; ni < 8; ++ni)
#pragma unroll
            for (int r = 0; r < 4; ++r)
                plw[(lg * 4 + r) * 136 + ni * 16 + lr] = __float2bfloat16(s[ni][r]);
        // per-wave fence: all LDS writes visible before cross-lane reads
        asm volatile("s_waitcnt lgkmcnt(0)" ::: "memory");
        const bf16* vk = vtb + kt * 128;
#pragma unroll
        for (int ks = 0; ks < 4; ++ks) {
            bf16x8_t pf = *(const bf16x8_t*)&plw[lr * 136 + ks * 32 + lg * 8];
#pragma unroll
            for (int ni = 0; ni < 4; ++ni) {
                bf16x8_t vf = *(const bf16x8_t*)(vk + (size_t)(ni * 16 + lr) * SEQ + ks * 32 + lg * 8);
                o[ni] = MFMA(pf, vf, o[ni]);
            }
        }
    }

    // ---- normalize and write ctx (bf16, natural (4096,1024) layout) ----
#pragma unroll
    for (int r = 0; r < 4; ++r) {
        float inv = 1.0f / lrow[r];
        int row = b * SEQ + m0 + lg * 4 + r;
#pragma unroll
        for (int ni = 0; ni < 4; ++ni)
            Ctx[(size_t)row * DIM + h * HD + ni * 16 + lr] =
                __float2bfloat16(o[ni][r] * inv);
    }
}

// ---------------- output projection GEMM -> fp32 d_out ----------------
__global__ __launch_bounds__(256) void k_gemm_out(const bf16* __restrict__ A,
                                                  const bf16* __restrict__ Bt,
                                                  const float* __restrict__ bias,
                                                  float* __restrict__ Out) {
    constexpr int K = DIM;
    __shared__ bf16 As[128 * 32];
    __shared__ bf16 Bs[128 * 32];
    int t = threadIdx.x;
    int l = t & 63;
    int w = t >> 6;
    int lr = l & 15, lg = l >> 4;
    int wr = w >> 1, wc = w & 1;
    int m0 = blockIdx.x * 128;
    int n0 = blockIdx.y * 128;

    f32x4_t acc[4][4] = {};

    int sr = t >> 2;
    int sc = (t & 3) * 8;
    const bf16* ga = A + (size_t)(m0 + sr) * K + sc;
    const bf16* gb = Bt + (size_t)(n0 + sr) * K + sc;
    bf16* wa = As + t * 8;
    bf16* wb = Bs + t * 8;

    for (int k0 = 0; k0 < K; k0 += 32) {
        gload_lds16(ga, wa);
        gload_lds16(ga + (size_t)64 * K, wa + 2048);
        gload_lds16(gb, wb);
        gload_lds16(gb + (size_t)64 * K, wb + 2048);
        ga += 32; gb += 32;
        __syncthreads();
        bf16x8_t af[4], bfv[4];
#pragma unroll
        for (int mi = 0; mi < 4; ++mi)
            af[mi] = *(const bf16x8_t*)&As[(wr * 64 + mi * 16 + lr) * 32 + lg * 8];
#pragma unroll
        for (int ni = 0; ni < 4; ++ni)
            bfv[ni] = *(const bf16x8_t*)&Bs[(wc * 64 + ni * 16 + lr) * 32 + lg * 8];
#pragma unroll
        for (int mi = 0; mi < 4; ++mi)
#pragma unroll
            for (int ni = 0; ni < 4; ++ni)
                acc[mi][ni] = MFMA(af[mi], bfv[ni], acc[mi][ni]);
        __syncthreads();
    }

    int nl = n0 + wc * 64;
#pragma unroll
    for (int mi = 0; mi < 4; ++mi) {
#pragma unroll
        for (int ni = 0; ni < 4; ++ni) {
            int row = m0 + wr * 64 + mi * 16 + lg * 4;
            int col = nl + ni * 16 + lr;
            float bb = bias[col];
#pragma unroll
            for (int r = 0; r < 4; ++r)
                Out[(size_t)(row + r) * DIM + col] = acc[mi][ni][r] + bb;
        }
    }
}

extern "C" void kernel_launch(void* const* d_in, const int* in_sizes, int n_in,
                              void* d_out, int out_size, void* d_ws, size_t ws_size,
                              hipStream_t stream) {
    const float* x  = (const float*)d_in[0];
    const int*   am = (const int*)d_in[1];
    const float* Wq = (const float*)d_in[2];
    const float* bq = (const float*)d_in[3];
    const float* Wk = (const float*)d_in[4];
    const float* bk = (const float*)d_in[5];
    const float* Wv = (const float*)d_in[6];
    const float* bv = (const float*)d_in[7];
    const float* Wo = (const float*)d_in[8];
    const float* bo = (const float*)d_in[9];

    char* ws = (char*)d_ws;
    const size_t MB = (size_t)1 << 20;
    bf16* xb  = (bf16*)(ws + 0 * MB);
    bf16* Wt  = (bf16*)(ws + 8 * MB);
    bf16* Qb  = (bf16*)(ws + 16 * MB);   // Q|K|V contiguous (24 MB)
    bf16* Vb  = (bf16*)(ws + 32 * MB);
    bf16* Vt  = (bf16*)(ws + 40 * MB);
    bf16* Ctx = (bf16*)(ws + 48 * MB);

    k_convert_x<<<dim3(MROWS * DIM / 4 / 256), 256, 0, stream>>>(
        (const float4*)x, (ushort4*)xb);
    k_transpose_w<<<dim3(16, 16, 4), 256, 0, stream>>>(Wq, Wk, Wv, Wo, Wt);
    k_gemm_qkv<<<dim3(32, 24), 256, 0, stream>>>(xb, Wt, bq, bk, bv, Qb);
    k_transpose_v<<<dim3(32, 32), 256, 0, stream>>>(Vb, Vt);
    k_attn<<<dim3(32, 32), 256, 0, stream>>>(Qb, Qb + (size_t)MROWS * DIM, Vt, am, Ctx);
    k_gemm_out<<<dim3(32, 8), 256, 0, stream>>>(Ctx, Wt + (size_t)3 * DIM * DIM, bo,
                                                (float*)d_out);
}

// Round 3
// 257.120 us; speedup vs baseline: 1.5797x; 1.5048x over previous
//
#include <hip/hip_runtime.h>
#include <hip/hip_bf16.h>

// MultiHeadSelfAttention on MI355X (gfx950), bf16 MFMA pipeline.
// Workspace layout (needs 56 MB):
//   [ 0MB) xb   : x as bf16            (4096x1024)
//   [ 8MB) Wt   : Wq^T|Wk^T|Wv^T|Wo^T  (4 x 1024x1024 bf16)
//   [16MB) Qb   : Q (pre-scaled 0.125) (4096x1024 bf16)
//   [24MB) Kb   : K                    (4096x1024 bf16)
//   [32MB) Vb   : V                    (4096x1024 bf16)
//   [40MB) Vt   : V^T per head         (2,16,64,2048 bf16)
//   [48MB) Ctx  : attention output     (4096x1024 bf16)

using bf16 = __hip_bfloat16;
typedef __attribute__((ext_vector_type(8))) short bf16x8_t;
typedef __attribute__((ext_vector_type(4))) float f32x4_t;

#define MFMA(a, b, c) __builtin_amdgcn_mfma_f32_16x16x32_bf16((a), (b), (c), 0, 0, 0)

constexpr int SEQ = 2048;
constexpr int DIM = 1024;
constexpr int HD  = 64;
constexpr int MROWS = 2 * SEQ;  // 4096

// async global->LDS, 16B per lane (m97 pattern). LDS dest must be
// wave-uniform base + lane*16 in lane order (m104) — our layouts are.
__device__ __forceinline__ void gload_lds16(const bf16* g, bf16* l) {
    __builtin_amdgcn_global_load_lds(
        (const __attribute__((address_space(1))) unsigned int*)g,
        (__attribute__((address_space(3))) unsigned int*)l, 16, 0, 0);
}

// ---------------- convert x: fp32 -> bf16, 4 elems/thread ----------------
__global__ __launch_bounds__(256) void k_convert_x(const float4* __restrict__ x,
                                                   ushort4* __restrict__ xb) {
    int i = blockIdx.x * 256 + threadIdx.x;
    float4 v = x[i];
    ushort4 o;
    o.x = __builtin_bit_cast(unsigned short, __float2bfloat16(v.x));
    o.y = __builtin_bit_cast(unsigned short, __float2bfloat16(v.y));
    o.z = __builtin_bit_cast(unsigned short, __float2bfloat16(v.z));
    o.w = __builtin_bit_cast(unsigned short, __float2bfloat16(v.w));
    xb[i] = o;
}

// -------- transpose+convert weights: W (k,n) fp32 -> Wt (n,k) bf16 --------
__global__ __launch_bounds__(256) void k_transpose_w(const float* __restrict__ W0,
                                                     const float* __restrict__ W1,
                                                     const float* __restrict__ W2,
                                                     const float* __restrict__ W3,
                                                     bf16* __restrict__ Wt) {
    const float* W = blockIdx.z == 0 ? W0 : blockIdx.z == 1 ? W1
                   : blockIdx.z == 2 ? W2 : W3;
    bf16* out = Wt + (size_t)blockIdx.z * DIM * DIM;
    __shared__ float tile[64][65];
    int r0 = blockIdx.x * 64, c0 = blockIdx.y * 64;
    int t = threadIdx.x;
    int c = t & 63, rq = t >> 6;
#pragma unroll
    for (int j = 0; j < 16; ++j) {
        int r = rq + j * 4;
        tile[r][c] = W[(size_t)(r0 + r) * DIM + c0 + c];
    }
    __syncthreads();
#pragma unroll
    for (int j = 0; j < 16; ++j) {
        int n = rq + j * 4;
        out[(size_t)(c0 + n) * DIM + r0 + c] = __float2bfloat16(tile[c][n]);
    }
}

// ---------------- fused QKV GEMM: 128x128 tile, 4 waves ----------------
// A (4096,1024) bf16; Bt = Wq^T|Wk^T|Wv^T (3072,1024); Out = Q|K|V contiguous.
__global__ __launch_bounds__(256) void k_gemm_qkv(const bf16* __restrict__ A,
                                                  const bf16* __restrict__ Bt,
                                                  const float* __restrict__ bq,
                                                  const float* __restrict__ bk,
                                                  const float* __restrict__ bv,
                                                  bf16* __restrict__ Out) {
    constexpr int K = DIM;
    __shared__ bf16 As[128 * 32];
    __shared__ bf16 Bs[128 * 32];
    int t = threadIdx.x;
    int l = t & 63;
    int w = t >> 6;
    int lr = l & 15, lg = l >> 4;
    int wr = w >> 1, wc = w & 1;
    int m0 = blockIdx.x * 128;
    int n0 = blockIdx.y * 128;

    f32x4_t acc[4][4] = {};

    int sr = t >> 2;           // staging row 0..63
    int sc = (t & 3) * 8;      // staging col chunk
    const bf16* ga = A + (size_t)(m0 + sr) * K + sc;
    const bf16* gb = Bt + (size_t)(n0 + sr) * K + sc;
    bf16* wa = As + t * 8;     // lane-ordered contiguous 16B slots
    bf16* wb = Bs + t * 8;

    for (int k0 = 0; k0 < K; k0 += 32) {
        gload_lds16(ga, wa);
        gload_lds16(ga + (size_t)64 * K, wa + 2048);
        gload_lds16(gb, wb);
        gload_lds16(gb + (size_t)64 * K, wb + 2048);
        ga += 32; gb += 32;
        __syncthreads();   // drains vmcnt -> LDS tiles ready
        bf16x8_t af[4], bfv[4];
#pragma unroll
        for (int mi = 0; mi < 4; ++mi)
            af[mi] = *(const bf16x8_t*)&As[(wr * 64 + mi * 16 + lr) * 32 + lg * 8];
#pragma unroll
        for (int ni = 0; ni < 4; ++ni)
            bfv[ni] = *(const bf16x8_t*)&Bs[(wc * 64 + ni * 16 + lr) * 32 + lg * 8];
#pragma unroll
        for (int mi = 0; mi < 4; ++mi)
#pragma unroll
            for (int ni = 0; ni < 4; ++ni)
                acc[mi][ni] = MFMA(af[mi], bfv[ni], acc[mi][ni]);
        __syncthreads();
    }

    int seg = n0 >> 10;  // 0=Q 1=K 2=V
    int nl = (n0 & 1023) + wc * 64;
    const float* bias = seg == 0 ? bq : seg == 1 ? bk : bv;
    float alpha = seg == 0 ? 0.125f : 1.0f;  // fold 1/sqrt(hd) into Q
    bf16* outp = Out + (size_t)seg * MROWS * DIM;
#pragma unroll
    for (int mi = 0; mi < 4; ++mi) {
#pragma unroll
        for (int ni = 0; ni < 4; ++ni) {
            int row = m0 + wr * 64 + mi * 16 + lg * 4;
            int col = nl + ni * 16 + lr;
            float bb = bias[col];
#pragma unroll
            for (int r = 0; r < 4; ++r) {
                float v = (acc[mi][ni][r] + bb) * alpha;
                outp[(size_t)(row + r) * DIM + col] = __float2bfloat16(v);
            }
        }
    }
}

// ------------- transpose V: (4096,1024) -> Vt (2,16,64,2048) -------------
__global__ __launch_bounds__(256) void k_transpose_v(const bf16* __restrict__ Vb,
                                                     bf16* __restrict__ Vt) {
    int s0 = blockIdx.x * 64;
    int bh = blockIdx.y;
    int b = bh >> 4, h = bh & 15;
    __shared__ bf16 tile[64][66];
    int t = threadIdx.x;
    int c = t & 63, rq = t >> 6;
#pragma unroll
    for (int j = 0; j < 16; ++j) {
        int s = rq + j * 4;
        tile[s][c] = Vb[(size_t)(b * SEQ + s0 + s) * DIM + h * HD + c];
    }
    __syncthreads();
#pragma unroll
    for (int j = 0; j < 16; ++j) {
        int d = rq + j * 4;
        Vt[((size_t)bh * HD + d) * SEQ + s0 + c] = tile[c][d];
    }
}

// ---- flash attention: 128 q-rows/block, 8 waves, LDS-staged K/V tiles ----
// K/V tiles staged once per block (global_load_lds w16), double-buffered,
// prefetch issued one tile ahead (m97 structure). XOR-swizzled layouts
// (byte ^= (row&7)<<4) applied via pre-swizzled global source addresses.
__global__ __launch_bounds__(512) void k_attn(const bf16* __restrict__ Qb,
                                              const bf16* __restrict__ Kb,
                                              const bf16* __restrict__ Vt,
                                              const int* __restrict__ amask,
                                              bf16* __restrict__ Ctx) {
    int qt = 15 - blockIdx.x;          // heavy (long-span) blocks first
    int bh = blockIdx.y;
    int b = bh >> 4, h = bh & 15;
    int t = threadIdx.x;
    int w = t >> 6, l = t & 63;
    int lr = l & 15, lg = l >> 4;
    int m0 = qt * 128 + w * 16;        // this wave's 16 q-rows

    __shared__ bf16 Kl[2][128 * 64];   // [key][hd], swizzled, 16KB each
    __shared__ bf16 Vl[2][64 * 128];   // [hd][key], swizzled, 16KB each
    __shared__ bf16 Pl[8][16 * 136];   // per-wave P scratch

    const bf16* vtb   = Vt + (size_t)bh * HD * SEQ;
    const bf16* kbase = Kb + ((size_t)b * SEQ) * DIM + h * HD;

    auto stage = [&](int kt, int bufi) {
#pragma unroll
        for (int c = 0; c < 2; ++c) {   // K tile: 16KB, 512 lanes x 16B x 2
            int P = t * 16 + c * 8192;
            int row = P >> 7;                        // key row 0..127
            int Lb = (P & 127) ^ ((row & 7) << 4);   // logical byte in row
            gload_lds16(kbase + (size_t)(kt * 128 + row) * DIM + (Lb >> 1),
                        (bf16*)((char*)&Kl[bufi][0] + P));
        }
#pragma unroll
        for (int c = 0; c < 2; ++c) {   // V^T tile
            int P = t * 16 + c * 8192;
            int row = P >> 8;                        // hd row 0..63
            int Lb = (P & 255) ^ ((row & 7) << 4);
            gload_lds16(vtb + (size_t)row * SEQ + kt * 128 + (Lb >> 1),
                        (bf16*)((char*)&Vl[bufi][0] + P));
        }
    };

    int nkt = qt + 1;                  // causal: kv tiles 0..qt
    stage(0, 0);

    // Q fragments (pre-scaled 0.125) into registers, overlapped with DMA
    const bf16* qbase = Qb + (size_t)(b * SEQ + m0 + lr) * DIM + h * HD;
    bf16x8_t qf[2];
#pragma unroll
    for (int ks = 0; ks < 2; ++ks)
        qf[ks] = *(const bf16x8_t*)(qbase + ks * 32 + lg * 8);

    f32x4_t o[4] = {};
    float mrow[4], lrow[4];
#pragma unroll
    for (int r = 0; r < 4; ++r) { mrow[r] = -1e30f; lrow[r] = 0.f; }

    bf16* plw = &Pl[w][0];
    const int swz = (lr & 7) << 4;

    __syncthreads();                   // K[0],V[0] ready
    int buf = 0;
    for (int kt = 0; kt < nkt; ++kt) {
        if (kt + 1 < nkt) stage(kt + 1, buf ^ 1);   // async prefetch
        const bf16* Klb = &Kl[buf][0];
        const bf16* Vlb = &Vl[buf][0];

        // ---- scores S = Q K^T (pre-scaled), 128 keys, from LDS ----
        f32x4_t s[8];
#pragma unroll
        for (int ni = 0; ni < 8; ++ni) {
            f32x4_t a = {0.f, 0.f, 0.f, 0.f};
            const char* kb = (const char*)Klb + (ni * 16 + lr) * 128;
#pragma unroll
            for (int ks = 0; ks < 2; ++ks) {
                bf16x8_t kf = *(const bf16x8_t*)(kb + ((ks * 64 + lg * 16) ^ swz));
                a = MFMA(qf[ks], kf, a);
            }
            s[ni] = a;
        }
        // ---- causal + padding mask ----
#pragma unroll
        for (int ni = 0; ni < 8; ++ni) {
            int key = kt * 128 + ni * 16 + lr;
            bool kv = amask[b * SEQ + key] > 0;
#pragma unroll
            for (int r = 0; r < 4; ++r) {
                int qrow = m0 + lg * 4 + r;
                if (!kv || key > qrow) s[ni][r] = -1e30f;
            }
        }
        // ---- online softmax: row stats via 16-lane shfl reductions ----
        float tm[4];
#pragma unroll
        for (int r = 0; r < 4; ++r) {
            float a0 = fmaxf(fmaxf(s[0][r], s[1][r]), fmaxf(s[2][r], s[3][r]));
            float a1 = fmaxf(fmaxf(s[4][r], s[5][r]), fmaxf(s[6][r], s[7][r]));
            tm[r] = fmaxf(a0, a1);
            tm[r] = fmaxf(tm[r], __shfl_xor(tm[r], 1));
            tm[r] = fmaxf(tm[r], __shfl_xor(tm[r], 2));
            tm[r] = fmaxf(tm[r], __shfl_xor(tm[r], 4));
            tm[r] = fmaxf(tm[r], __shfl_xor(tm[r], 8));
        }
        float rs[4];
#pragma unroll
        for (int r = 0; r < 4; ++r) {
            float mnew = fmaxf(mrow[r], tm[r]);
            float al = __expf(mrow[r] - mnew);
            mrow[r] = mnew;
            lrow[r] *= al;
            rs[r] = 0.f;
#pragma unroll
            for (int ni = 0; ni < 8; ++ni) {
                float p = __expf(s[ni][r] - mnew);
                s[ni][r] = p;
                rs[r] += p;
            }
#pragma unroll
            for (int ni = 0; ni < 4; ++ni)
                o[ni][r] *= al;
        }
#pragma unroll
        for (int r = 0; r < 4; ++r) {
            rs[r] += __shfl_xor(rs[r], 1);
            rs[r] += __shfl_xor(rs[r], 2);
            rs[r] += __shfl_xor(rs[r], 4);
            rs[r] += __shfl_xor(rs[r], 8);
            lrow[r] += rs[r];
        }
        // ---- P (C-layout) -> per-wave LDS -> A-layout for PV ----
        asm volatile("" ::: "memory");
#pragma unroll
        for (int ni = 0; ni < 8; ++ni)
#pragma unroll
            for (int r = 0; r < 4; ++r)
                plw[(lg * 4 + r) * 136 + ni * 16 + lr] = __float2bfloat16(s[ni][r]);
        asm volatile("s_waitcnt lgkmcnt(0)" ::: "memory");
        __builtin_amdgcn_sched_barrier(0);
        // ---- PV from staged V^T ----
#pragma unroll
        for (int ks = 0; ks < 4; ++ks) {
            bf16x8_t pf = *(const bf16x8_t*)&plw[lr * 136 + ks * 32 + lg * 8];
#pragma unroll
            for (int ni = 0; ni < 4; ++ni) {
                const char* vb = (const char*)Vlb + (ni * 16 + lr) * 256;
                bf16x8_t vf = *(const bf16x8_t*)(vb + ((ks * 64 + lg * 16) ^ swz));
                o[ni] = MFMA(pf, vf, o[ni]);
            }
        }
        __syncthreads();               // drain prefetch + buffer handoff
        buf ^= 1;
    }

    // ---- normalize and write ctx (bf16, natural (4096,1024) layout) ----
#pragma unroll
    for (int r = 0; r < 4; ++r) {
        float inv = 1.0f / lrow[r];
        int row = b * SEQ + m0 + lg * 4 + r;
#pragma unroll
        for (int ni = 0; ni < 4; ++ni)
            Ctx[(size_t)row * DIM + h * HD + ni * 16 + lr] =
                __float2bfloat16(o[ni][r] * inv);
    }
}

// ---------------- output projection GEMM -> fp32 d_out ----------------
__global__ __launch_bounds__(256) void k_gemm_out(const bf16* __restrict__ A,
                                                  const bf16* __restrict__ Bt,
                                                  const float* __restrict__ bias,
                                                  float* __restrict__ Out) {
    constexpr int K = DIM;
    __shared__ bf16 As[128 * 32];
    __shared__ bf16 Bs[128 * 32];
    int t = threadIdx.x;
    int l = t & 63;
    int w = t >> 6;
    int lr = l & 15, lg = l >> 4;
    int wr = w >> 1, wc = w & 1;
    int m0 = blockIdx.x * 128;
    int n0 = blockIdx.y * 128;

    f32x4_t acc[4][4] = {};

    int sr = t >> 2;
    int sc = (t & 3) * 8;
    const bf16* ga = A + (size_t)(m0 + sr) * K + sc;
    const bf16* gb = Bt + (size_t)(n0 + sr) * K + sc;
    bf16* wa = As + t * 8;
    bf16* wb = Bs + t * 8;

    for (int k0 = 0; k0 < K; k0 += 32) {
        gload_lds16(ga, wa);
        gload_lds16(ga + (size_t)64 * K, wa + 2048);
        gload_lds16(gb, wb);
        gload_lds16(gb + (size_t)64 * K, wb + 2048);
        ga += 32; gb += 32;
        __syncthreads();
        bf16x8_t af[4], bfv[4];
#pragma unroll
        for (int mi = 0; mi < 4; ++mi)
            af[mi] = *(const bf16x8_t*)&As[(wr * 64 + mi * 16 + lr) * 32 + lg * 8];
#pragma unroll
        for (int ni = 0; ni < 4; ++ni)
            bfv[ni] = *(const bf16x8_t*)&Bs[(wc * 64 + ni * 16 + lr) * 32 + lg * 8];
#pragma unroll
        for (int mi = 0; mi < 4; ++mi)
#pragma unroll
            for (int ni = 0; ni < 4; ++ni)
                acc[mi][ni] = MFMA(af[mi], bfv[ni], acc[mi][ni]);
        __syncthreads();
    }

    int nl = n0 + wc * 64;
#pragma unroll
    for (int mi = 0; mi < 4; ++mi) {
#pragma unroll
        for (int ni = 0; ni < 4; ++ni) {
            int row = m0 + wr * 64 + mi * 16 + lg * 4;
            int col = nl + ni * 16 + lr;
            float bb = bias[col];
#pragma unroll
            for (int r = 0; r < 4; ++r)
                Out[(size_t)(row + r) * DIM + col] = acc[mi][ni][r] + bb;
        }
    }
}

extern "C" void kernel_launch(void* const* d_in, const int* in_sizes, int n_in,
                              void* d_out, int out_size, void* d_ws, size_t ws_size,
                              hipStream_t stream) {
    const float* x  = (const float*)d_in[0];
    const int*   am = (const int*)d_in[1];
    const float* Wq = (const float*)d_in[2];
    const float* bq = (const float*)d_in[3];
    const float* Wk = (const float*)d_in[4];
    const float* bk = (const float*)d_in[5];
    const float* Wv = (const float*)d_in[6];
    const float* bv = (const float*)d_in[7];
    const float* Wo = (const float*)d_in[8];
    const float* bo = (const float*)d_in[9];

    char* ws = (char*)d_ws;
    const size_t MB = (size_t)1 << 20;
    bf16* xb  = (bf16*)(ws + 0 * MB);
    bf16* Wt  = (bf16*)(ws + 8 * MB);
    bf16* Qb  = (bf16*)(ws + 16 * MB);   // Q|K|V contiguous (24 MB)
    bf16* Vb  = (bf16*)(ws + 32 * MB);
    bf16* Vt  = (bf16*)(ws + 40 * MB);
    bf16* Ctx = (bf16*)(ws + 48 * MB);

    k_convert_x<<<dim3(MROWS * DIM / 4 / 256), 256, 0, stream>>>(
        (const float4*)x, (ushort4*)xb);
    k_transpose_w<<<dim3(16, 16, 4), 256, 0, stream>>>(Wq, Wk, Wv, Wo, Wt);
    k_gemm_qkv<<<dim3(32, 24), 256, 0, stream>>>(xb, Wt, bq, bk, bv, Qb);
    k_transpose_v<<<dim3(32, 32), 256, 0, stream>>>(Vb, Vt);
    k_attn<<<dim3(16, 32), 512, 0, stream>>>(Qb, Qb + (size_t)MROWS * DIM, Vt, am, Ctx);
    k_gemm_out<<<dim3(32, 8), 256, 0, stream>>>(Ctx, Wt + (size_t)3 * DIM * DIM, bo,
                                                (float*)d_out);
}

// Round 5
// 233.324 us; speedup vs baseline: 1.7408x; 1.1020x over previous
//
#include <hip/hip_runtime.h>
#include <hip/hip_bf16.h>

// MultiHeadSelfAttention on MI355X (gfx950), bf16 MFMA pipeline.
// Workspace layout (needs 56 MB):
//   [ 0MB) xb   : x as bf16            (4096x1024)
//   [ 8MB) Wt   : Wq^T|Wk^T|Wv^T|Wo^T  (4 x 1024x1024 bf16)
//   [16MB) Qb   : Q (pre-scaled 0.125) (4096x1024 bf16)
//   [24MB) Kb   : K                    (4096x1024 bf16)
//   [32MB) Vb   : V                    (4096x1024 bf16)
//   [40MB) Vt   : V^T per head         (2,16,64,2048 bf16)
//   [48MB) Ctx  : attention output     (4096x1024 bf16)

using bf16 = __hip_bfloat16;
typedef __attribute__((ext_vector_type(8))) short bf16x8_t;
typedef __attribute__((ext_vector_type(4))) float f32x4_t;

#define MFMA(a, b, c) __builtin_amdgcn_mfma_f32_16x16x32_bf16((a), (b), (c), 0, 0, 0)

constexpr int SEQ = 2048;
constexpr int DIM = 1024;
constexpr int HD  = 64;
constexpr int MROWS = 2 * SEQ;  // 4096

// async global->LDS, 16B per lane (m97 pattern). LDS dest must be
// wave-uniform base + lane*16 in lane order (m104) — our layouts are.
__device__ __forceinline__ void gload_lds16(const bf16* g, bf16* l) {
    __builtin_amdgcn_global_load_lds(
        (const __attribute__((address_space(1))) unsigned int*)g,
        (__attribute__((address_space(3))) unsigned int*)l, 16, 0, 0);
}

__device__ __forceinline__ ushort4 pack4(f32x4_t v) {
    ushort4 u;
    u.x = __builtin_bit_cast(unsigned short, __float2bfloat16(v[0]));
    u.y = __builtin_bit_cast(unsigned short, __float2bfloat16(v[1]));
    u.z = __builtin_bit_cast(unsigned short, __float2bfloat16(v[2]));
    u.w = __builtin_bit_cast(unsigned short, __float2bfloat16(v[3]));
    return u;
}

// ---------------- convert x: fp32 -> bf16, 4 elems/thread ----------------
__global__ __launch_bounds__(256) void k_convert_x(const float4* __restrict__ x,
                                                   ushort4* __restrict__ xb) {
    int i = blockIdx.x * 256 + threadIdx.x;
    float4 v = x[i];
    ushort4 o;
    o.x = __builtin_bit_cast(unsigned short, __float2bfloat16(v.x));
    o.y = __builtin_bit_cast(unsigned short, __float2bfloat16(v.y));
    o.z = __builtin_bit_cast(unsigned short, __float2bfloat16(v.z));
    o.w = __builtin_bit_cast(unsigned short, __float2bfloat16(v.w));
    xb[i] = o;
}

// -------- transpose+convert weights: W (k,n) fp32 -> Wt (n,k) bf16 --------
__global__ __launch_bounds__(256) void k_transpose_w(const float* __restrict__ W0,
                                                     const float* __restrict__ W1,
                                                     const float* __restrict__ W2,
                                                     const float* __restrict__ W3,
                                                     bf16* __restrict__ Wt) {
    const float* W = blockIdx.z == 0 ? W0 : blockIdx.z == 1 ? W1
                   : blockIdx.z == 2 ? W2 : W3;
    bf16* out = Wt + (size_t)blockIdx.z * DIM * DIM;
    __shared__ float tile[64][65];
    int r0 = blockIdx.x * 64, c0 = blockIdx.y * 64;
    int t = threadIdx.x;
    int c = t & 63, rq = t >> 6;
#pragma unroll
    for (int j = 0; j < 16; ++j) {
        int r = rq + j * 4;
        tile[r][c] = W[(size_t)(r0 + r) * DIM + c0 + c];
    }
    __syncthreads();
#pragma unroll
    for (int j = 0; j < 16; ++j) {
        int n = rq + j * 4;
        out[(size_t)(c0 + n) * DIM + r0 + c] = __float2bfloat16(tile[c][n]);
    }
}

// ---------------- fused QKV GEMM: 128x128 tile, 4 waves ----------------
// A (4096,1024) bf16; Bt = Wq^T|Wk^T|Wv^T (3072,1024); Out = Q|K|V contiguous.
__global__ __launch_bounds__(256) void k_gemm_qkv(const bf16* __restrict__ A,
                                                  const bf16* __restrict__ Bt,
                                                  const float* __restrict__ bq,
                                                  const float* __restrict__ bk,
                                                  const float* __restrict__ bv,
                                                  bf16* __restrict__ Out) {
    constexpr int K = DIM;
    __shared__ bf16 As[128 * 32];
    __shared__ bf16 Bs[128 * 32];
    int t = threadIdx.x;
    int l = t & 63;
    int w = t >> 6;
    int lr = l & 15, lg = l >> 4;
    int wr = w >> 1, wc = w & 1;
    int m0 = blockIdx.x * 128;
    int n0 = blockIdx.y * 128;

    f32x4_t acc[4][4] = {};

    int sr = t >> 2;           // staging row 0..63
    int sc = (t & 3) * 8;      // staging col chunk
    const bf16* ga = A + (size_t)(m0 + sr) * K + sc;
    const bf16* gb = Bt + (size_t)(n0 + sr) * K + sc;
    bf16* wa = As + t * 8;     // lane-ordered contiguous 16B slots
    bf16* wb = Bs + t * 8;

    for (int k0 = 0; k0 < K; k0 += 32) {
        gload_lds16(ga, wa);
        gload_lds16(ga + (size_t)64 * K, wa + 2048);
        gload_lds16(gb, wb);
        gload_lds16(gb + (size_t)64 * K, wb + 2048);
        ga += 32; gb += 32;
        __syncthreads();   // drains vmcnt -> LDS tiles ready
        bf16x8_t af[4], bfv[4];
#pragma unroll
        for (int mi = 0; mi < 4; ++mi)
            af[mi] = *(const bf16x8_t*)&As[(wr * 64 + mi * 16 + lr) * 32 + lg * 8];
#pragma unroll
        for (int ni = 0; ni < 4; ++ni)
            bfv[ni] = *(const bf16x8_t*)&Bs[(wc * 64 + ni * 16 + lr) * 32 + lg * 8];
#pragma unroll
        for (int mi = 0; mi < 4; ++mi)
#pragma unroll
            for (int ni = 0; ni < 4; ++ni)
                acc[mi][ni] = MFMA(af[mi], bfv[ni], acc[mi][ni]);
        __syncthreads();
    }

    int seg = n0 >> 10;  // 0=Q 1=K 2=V
    int nl = (n0 & 1023) + wc * 64;
    const float* bias = seg == 0 ? bq : seg == 1 ? bk : bv;
    float alpha = seg == 0 ? 0.125f : 1.0f;  // fold 1/sqrt(hd) into Q
    bf16* outp = Out + (size_t)seg * MROWS * DIM;
#pragma unroll
    for (int mi = 0; mi < 4; ++mi) {
#pragma unroll
        for (int ni = 0; ni < 4; ++ni) {
            int row = m0 + wr * 64 + mi * 16 + lg * 4;
            int col = nl + ni * 16 + lr;
            float bb = bias[col];
#pragma unroll
            for (int r = 0; r < 4; ++r) {
                float v = (acc[mi][ni][r] + bb) * alpha;
                outp[(size_t)(row + r) * DIM + col] = __float2bfloat16(v);
            }
        }
    }
}

// ------------- transpose V: (4096,1024) -> Vt (2,16,64,2048) -------------
__global__ __launch_bounds__(256) void k_transpose_v(const bf16* __restrict__ Vb,
                                                     bf16* __restrict__ Vt) {
    int s0 = blockIdx.x * 64;
    int bh = blockIdx.y;
    int b = bh >> 4, h = bh & 15;
    __shared__ bf16 tile[64][66];
    int t = threadIdx.x;
    int c = t & 63, rq = t >> 6;
#pragma unroll
    for (int j = 0; j < 16; ++j) {
        int s = rq + j * 4;
        tile[s][c] = Vb[(size_t)(b * SEQ + s0 + s) * DIM + h * HD + c];
    }
    __syncthreads();
#pragma unroll
    for (int j = 0; j < 16; ++j) {
        int d = rq + j * 4;
        Vt[((size_t)bh * HD + d) * SEQ + s0 + c] = tile[c][d];
    }
}

// ---- flash attention, swapped-operand form (one q-row per lane) ----
// 4 waves x 32 q-rows = 128 q/block; KVBLK=64; K/V staged via
// global_load_lds w16 double-buffered, XOR-swizzled rows ((r&7)<<4 on
// 128B rows, applied via pre-swizzled global source).  mfma(K,Q) puts
// q on C-cols (lane-local): softmax = in-lane reduce + 2 shfls.
// Padding mask staged once as additive f32 bias in LDS.
__global__ __launch_bounds__(256) void k_attn(const bf16* __restrict__ Qb,
                                              const bf16* __restrict__ Kb,
                                              const bf16* __restrict__ Vt,
                                              const int* __restrict__ amask,
                                              bf16* __restrict__ Ctx) {
    int qt = 15 - blockIdx.x;          // heavy (long-span) blocks first
    int bh = blockIdx.y;
    int b = bh >> 4, h = bh & 15;
    int t = threadIdx.x;
    int w = t >> 6, l = t & 63;
    int lr = l & 15, lg = l >> 4;
    int m0 = qt * 128 + w * 32;        // wave's q-base (2 sub-tiles of 16)

    __shared__ bf16  Kl[2][64 * 64];   // [key][hd] swizzled, 8KB each
    __shared__ bf16  Vl[2][64 * 64];   // [hd][key] swizzled, 8KB each
    __shared__ float Bl[SEQ];          // additive key bias (0 / -1e30)
    __shared__ bf16  Ps[4][16 * 72];   // per-wave P scratch (16q x 64k + pad)

    const bf16* vtb   = Vt + (size_t)bh * HD * SEQ;
    const bf16* kbase = Kb + (size_t)b * SEQ * DIM + h * HD;

    auto stage = [&](int kt, int bufi) {
#pragma unroll
        for (int c = 0; c < 2; ++c) {  // K tile 8KB: 256 thr x 16B x 2
            int P = t * 16 + c * 4096;
            int row = P >> 7;                       // key row 0..63
            int Lb = (P & 127) ^ ((row & 7) << 4);  // swizzled byte in row
            gload_lds16(kbase + (size_t)(kt * 64 + row) * DIM + (Lb >> 1),
                        (bf16*)((char*)&Kl[bufi][0] + P));
        }
#pragma unroll
        for (int c = 0; c < 2; ++c) {  // V^T tile 8KB (rows d, 128B each)
            int P = t * 16 + c * 4096;
            int row = P >> 7;
            int Lb = (P & 127) ^ ((row & 7) << 4);
            gload_lds16(vtb + (size_t)row * SEQ + kt * 64 + (Lb >> 1),
                        (bf16*)((char*)&Vl[bufi][0] + P));
        }
    };

    int nkt = 2 * qt + 2;              // kv tiles of 64 keys
    stage(0, 0);

    // padding-mask bias: one pass, 8 keys/thread
#pragma unroll
    for (int j = 0; j < 2; ++j) {
        int4 a4 = ((const int4*)(amask + b * SEQ))[t * 2 + j];
        int i = (t * 2 + j) * 4;
        Bl[i + 0] = a4.x > 0 ? 0.f : -1e30f;
        Bl[i + 1] = a4.y > 0 ? 0.f : -1e30f;
        Bl[i + 2] = a4.z > 0 ? 0.f : -1e30f;
        Bl[i + 3] = a4.w > 0 ? 0.f : -1e30f;
    }

    // Q fragments (pre-scaled 0.125): 2 q-subtiles x 2 k-chunks
    const bf16* qbase = Qb + (size_t)(b * SEQ + m0 + lr) * DIM + h * HD;
    bf16x8_t qf[2][2];
#pragma unroll
    for (int qi = 0; qi < 2; ++qi)
#pragma unroll
        for (int ks = 0; ks < 2; ++ks)
            qf[qi][ks] = *(const bf16x8_t*)(qbase + (size_t)qi * 16 * DIM + ks * 32 + lg * 8);

    f32x4_t o[2][4] = {};
    float mrow[2] = {-1e30f, -1e30f}, lrow[2] = {0.f, 0.f};
    bf16* ps = &Ps[w][0];

    __syncthreads();                   // K[0],V[0],Bl ready
    int buf = 0;
    for (int kt = 0; kt < nkt; ++kt) {
        if (kt + 1 < nkt) stage(kt + 1, buf ^ 1);   // async prefetch
        const char* Klb = (const char*)&Kl[buf][0];
        const char* Vlb = (const char*)&Vl[buf][0];

        // ---- K fragments (shared across both q-subtiles) ----
        bf16x8_t kf[4][2];
#pragma unroll
        for (int ni = 0; ni < 4; ++ni) {
            int row = ni * 16 + lr;
#pragma unroll
            for (int ks = 0; ks < 2; ++ks)
                kf[ni][ks] = *(const bf16x8_t*)(Klb + row * 128 +
                                 ((ks * 64 + lg * 16) ^ ((row & 7) << 4)));
        }
        // ---- V^T fragments (shared across q-subtiles) ----
        bf16x8_t vf[4][2];
#pragma unroll
        for (int ni = 0; ni < 4; ++ni) {
            int row = ni * 16 + lr;
#pragma unroll
            for (int kc = 0; kc < 2; ++kc)
                vf[ni][kc] = *(const bf16x8_t*)(Vlb + row * 128 +
                                 ((kc * 64 + lg * 16) ^ ((row & 7) << 4)));
        }
        // ---- bias (key-only, shared across q) ----
        f32x4_t b4[4];
#pragma unroll
        for (int ni = 0; ni < 4; ++ni)
            b4[ni] = *(const f32x4_t*)&Bl[kt * 64 + ni * 16 + lg * 4];

#pragma unroll
        for (int qi = 0; qi < 2; ++qi) {
            // ---- scores: mfma(K, Q) -> C[key][q], q = lane-local (lr) ----
            f32x4_t s[4];
#pragma unroll
            for (int ni = 0; ni < 4; ++ni) {
                f32x4_t a = {0.f, 0.f, 0.f, 0.f};
                a = MFMA(kf[ni][0], qf[qi][0], a);
                a = MFMA(kf[ni][1], qf[qi][1], a);
                s[ni] = a + b4[ni];    // additive padding mask
            }
            // ---- causal mask (skip when tile fully below q range) ----
            int q = m0 + qi * 16 + lr;
            if (kt * 64 + 63 > m0 + qi * 16) {
#pragma unroll
                for (int ni = 0; ni < 4; ++ni)
#pragma unroll
                    for (int r = 0; r < 4; ++r) {
                        int key = kt * 64 + ni * 16 + lg * 4 + r;
                        if (key > q) s[ni][r] = -1e30f;
                    }
            }
            // ---- online softmax: 15 in-lane + 2 shfls ----
            float tm = fmaxf(fmaxf(fmaxf(s[0][0], s[0][1]), fmaxf(s[0][2], s[0][3])),
                             fmaxf(fmaxf(s[1][0], s[1][1]), fmaxf(s[1][2], s[1][3])));
            float tm2 = fmaxf(fmaxf(fmaxf(s[2][0], s[2][1]), fmaxf(s[2][2], s[2][3])),
                              fmaxf(fmaxf(s[3][0], s[3][1]), fmaxf(s[3][2], s[3][3])));
            tm = fmaxf(tm, tm2);
            tm = fmaxf(tm, __shfl_xor(tm, 16));
            tm = fmaxf(tm, __shfl_xor(tm, 32));
            float mnew = fmaxf(mrow[qi], tm);
            float al = __expf(mrow[qi] - mnew);
            mrow[qi] = mnew;
            float rs = 0.f;
#pragma unroll
            for (int ni = 0; ni < 4; ++ni) {
#pragma unroll
                for (int r = 0; r < 4; ++r) {
                    float p = __expf(s[ni][r] - mnew);
                    s[ni][r] = p;
                    rs += p;
                }
            }
            rs += __shfl_xor(rs, 16);
            rs += __shfl_xor(rs, 32);
            lrow[qi] = lrow[qi] * al + rs;
#pragma unroll
            for (int ni = 0; ni < 4; ++ni)
                o[qi][ni] *= al;
            // ---- P -> per-wave LDS (b64 rows by q) -> B-fragments ----
            asm volatile("" ::: "memory");
#pragma unroll
            for (int ni = 0; ni < 4; ++ni)
                *(ushort4*)&ps[lr * 72 + ni * 16 + lg * 4] = pack4(s[ni]);
            asm volatile("s_waitcnt lgkmcnt(0)" ::: "memory");
            __builtin_amdgcn_sched_barrier(0);
            bf16x8_t pf[2];
#pragma unroll
            for (int kc = 0; kc < 2; ++kc)
                pf[kc] = *(const bf16x8_t*)&ps[lr * 72 + kc * 32 + lg * 8];
            // ---- PV: mfma(V^T, P) -> O^T[d][q] ----
#pragma unroll
            for (int ni = 0; ni < 4; ++ni) {
                o[qi][ni] = MFMA(vf[ni][0], pf[0], o[qi][ni]);
                o[qi][ni] = MFMA(vf[ni][1], pf[1], o[qi][ni]);
            }
        }
        __syncthreads();               // drain prefetch + buffer handoff
        buf ^= 1;
    }

    // ---- normalize and write ctx: lane q = m0+qi*16+lr, d = ni*16+lg*4+r ----
#pragma unroll
    for (int qi = 0; qi < 2; ++qi) {
        float inv = 1.0f / lrow[qi];
        size_t row = (size_t)(b * SEQ + m0 + qi * 16 + lr);
#pragma unroll
        for (int ni = 0; ni < 4; ++ni) {
            f32x4_t v = o[qi][ni];
            v *= inv;
            *(ushort4*)&Ctx[row * DIM + h * HD + ni * 16 + lg * 4] = pack4(v);
        }
    }
}

// ---------------- output projection GEMM -> fp32 d_out ----------------
__global__ __launch_bounds__(256) void k_gemm_out(const bf16* __restrict__ A,
                                                  const bf16* __restrict__ Bt,
                                                  const float* __restrict__ bias,
                                                  float* __restrict__ Out) {
    constexpr int K = DIM;
    __shared__ bf16 As[128 * 32];
    __shared__ bf16 Bs[128 * 32];
    int t = threadIdx.x;
    int l = t & 63;
    int w = t >> 6;
    int lr = l & 15, lg = l >> 4;
    int wr = w >> 1, wc = w & 1;
    int m0 = blockIdx.x * 128;
    int n0 = blockIdx.y * 128;

    f32x4_t acc[4][4] = {};

    int sr = t >> 2;
    int sc = (t & 3) * 8;
    const bf16* ga = A + (size_t)(m0 + sr) * K + sc;
    const bf16* gb = Bt + (size_t)(n0 + sr) * K + sc;
    bf16* wa = As + t * 8;
    bf16* wb = Bs + t * 8;

    for (int k0 = 0; k0 < K; k0 += 32) {
        gload_lds16(ga, wa);
        gload_lds16(ga + (size_t)64 * K, wa + 2048);
        gload_lds16(gb, wb);
        gload_lds16(gb + (size_t)64 * K, wb + 2048);
        ga += 32; gb += 32;
        __syncthreads();
        bf16x8_t af[4], bfv[4];
#pragma unroll
        for (int mi = 0; mi < 4; ++mi)
            af[mi] = *(const bf16x8_t*)&As[(wr * 64 + mi * 16 + lr) * 32 + lg * 8];
#pragma unroll
        for (int ni = 0; ni < 4; ++ni)
            bfv[ni] = *(const bf16x8_t*)&Bs[(wc * 64 + ni * 16 + lr) * 32 + lg * 8];
#pragma unroll
        for (int mi = 0; mi < 4; ++mi)
#pragma unroll
            for (int ni = 0; ni < 4; ++ni)
                acc[mi][ni] = MFMA(af[mi], bfv[ni], acc[mi][ni]);
        __syncthreads();
    }

    int nl = n0 + wc * 64;
#pragma unroll
    for (int mi = 0; mi < 4; ++mi) {
#pragma unroll
        for (int ni = 0; ni < 4; ++ni) {
            int row = m0 + wr * 64 + mi * 16 + lg * 4;
            int col = nl + ni * 16 + lr;
            float bb = bias[col];
#pragma unroll
            for (int r = 0; r < 4; ++r)
                Out[(size_t)(row + r) * DIM + col] = acc[mi][ni][r] + bb;
        }
    }
}

extern "C" void kernel_launch(void* const* d_in, const int* in_sizes, int n_in,
                              void* d_out, int out_size, void* d_ws, size_t ws_size,
                              hipStream_t stream) {
    const float* x  = (const float*)d_in[0];
    const int*   am = (const int*)d_in[1];
    const float* Wq = (const float*)d_in[2];
    const float* bq = (const float*)d_in[3];
    const float* Wk = (const float*)d_in[4];
    const float* bk = (const float*)d_in[5];
    const float* Wv = (const float*)d_in[6];
    const float* bv = (const float*)d_in[7];
    const float* Wo = (const float*)d_in[8];
    const float* bo = (const float*)d_in[9];

    char* ws = (char*)d_ws;
    const size_t MB = (size_t)1 << 20;
    bf16* xb  = (bf16*)(ws + 0 * MB);
    bf16* Wt  = (bf16*)(ws + 8 * MB);
    bf16* Qb  = (bf16*)(ws + 16 * MB);   // Q|K|V contiguous (24 MB)
    bf16* Vb  = (bf16*)(ws + 32 * MB);
    bf16* Vt  = (bf16*)(ws + 40 * MB);
    bf16* Ctx = (bf16*)(ws + 48 * MB);

    k_convert_x<<<dim3(MROWS * DIM / 4 / 256), 256, 0, stream>>>(
        (const float4*)x, (ushort4*)xb);
    k_transpose_w<<<dim3(16, 16, 4), 256, 0, stream>>>(Wq, Wk, Wv, Wo, Wt);
    k_gemm_qkv<<<dim3(32, 24), 256, 0, stream>>>(xb, Wt, bq, bk, bv, Qb);
    k_transpose_v<<<dim3(32, 32), 256, 0, stream>>>(Vb, Vt);
    k_attn<<<dim3(16, 32), 256, 0, stream>>>(Qb, Qb + (size_t)MROWS * DIM, Vt, am, Ctx);
    k_gemm_out<<<dim3(32, 8), 256, 0, stream>>>(Ctx, Wt + (size_t)3 * DIM * DIM, bo,
                                                (float*)d_out);
}

// Round 6
// 216.363 us; speedup vs baseline: 1.8773x; 1.0784x over previous
//
#include <hip/hip_runtime.h>
#include <hip/hip_bf16.h>

// MultiHeadSelfAttention on MI355X (gfx950), bf16 MFMA pipeline.
// Workspace layout (needs 56 MB):
//   [ 0MB) xb   : x as bf16            (4096x1024)
//   [ 8MB) Wt   : Wq^T|Wk^T|Wv^T|Wo^T  (4 x 1024x1024 bf16)
//   [16MB) Qb   : Q (pre-scaled 0.125*log2e) (4096x1024 bf16)
//   [24MB) Kb   : K                    (4096x1024 bf16)
//   [32MB) Vb   : V                    (4096x1024 bf16)
//   [40MB) Vt   : V^T per head         (2,16,64,2048 bf16)
//   [48MB) Ctx  : attention output     (4096x1024 bf16)

using bf16 = __hip_bfloat16;
typedef __attribute__((ext_vector_type(8))) short bf16x8_t;
typedef __attribute__((ext_vector_type(4))) float f32x4_t;

#define MFMA(a, b, c) __builtin_amdgcn_mfma_f32_16x16x32_bf16((a), (b), (c), 0, 0, 0)

constexpr int SEQ = 2048;
constexpr int DIM = 1024;
constexpr int HD  = 64;
constexpr int MROWS = 2 * SEQ;  // 4096

// async global->LDS, 16B per lane (m97 pattern). LDS dest must be
// wave-uniform base + lane*16 in lane order (m104) — our layouts are.
__device__ __forceinline__ void gload_lds16(const bf16* g, bf16* l) {
    __builtin_amdgcn_global_load_lds(
        (const __attribute__((address_space(1))) unsigned int*)g,
        (__attribute__((address_space(3))) unsigned int*)l, 16, 0, 0);
}

__device__ __forceinline__ ushort4 pack4(f32x4_t v) {
    ushort4 u;
    u.x = __builtin_bit_cast(unsigned short, __float2bfloat16(v[0]));
    u.y = __builtin_bit_cast(unsigned short, __float2bfloat16(v[1]));
    u.z = __builtin_bit_cast(unsigned short, __float2bfloat16(v[2]));
    u.w = __builtin_bit_cast(unsigned short, __float2bfloat16(v[3]));
    return u;
}

// exp2 fast path (Q is pre-scaled by log2e so softmax uses raw v_exp_f32)
__device__ __forceinline__ float fexp2(float x) {
#if __has_builtin(__builtin_amdgcn_exp2f)
    return __builtin_amdgcn_exp2f(x);
#else
    return exp2f(x);
#endif
}

// ---------------- convert x: fp32 -> bf16, 4 elems/thread ----------------
__global__ __launch_bounds__(256) void k_convert_x(const float4* __restrict__ x,
                                                   ushort4* __restrict__ xb) {
    int i = blockIdx.x * 256 + threadIdx.x;
    float4 v = x[i];
    ushort4 o;
    o.x = __builtin_bit_cast(unsigned short, __float2bfloat16(v.x));
    o.y = __builtin_bit_cast(unsigned short, __float2bfloat16(v.y));
    o.z = __builtin_bit_cast(unsigned short, __float2bfloat16(v.z));
    o.w = __builtin_bit_cast(unsigned short, __float2bfloat16(v.w));
    xb[i] = o;
}

// -------- transpose+convert weights: W (k,n) fp32 -> Wt (n,k) bf16 --------
__global__ __launch_bounds__(256) void k_transpose_w(const float* __restrict__ W0,
                                                     const float* __restrict__ W1,
                                                     const float* __restrict__ W2,
                                                     const float* __restrict__ W3,
                                                     bf16* __restrict__ Wt) {
    const float* W = blockIdx.z == 0 ? W0 : blockIdx.z == 1 ? W1
                   : blockIdx.z == 2 ? W2 : W3;
    bf16* out = Wt + (size_t)blockIdx.z * DIM * DIM;
    __shared__ float tile[64][65];
    int r0 = blockIdx.x * 64, c0 = blockIdx.y * 64;
    int t = threadIdx.x;
    int c = t & 63, rq = t >> 6;
#pragma unroll
    for (int j = 0; j < 16; ++j) {
        int r = rq + j * 4;
        tile[r][c] = W[(size_t)(r0 + r) * DIM + c0 + c];
    }
    __syncthreads();
#pragma unroll
    for (int j = 0; j < 16; ++j) {
        int n = rq + j * 4;
        out[(size_t)(c0 + n) * DIM + r0 + c] = __float2bfloat16(tile[c][n]);
    }
}

// ---------------- fused QKV GEMM: 128x128 tile, 4 waves ----------------
// A (4096,1024) bf16; Bt = Wq^T|Wk^T|Wv^T (3072,1024); Out = Q|K|V contiguous.
__global__ __launch_bounds__(256) void k_gemm_qkv(const bf16* __restrict__ A,
                                                  const bf16* __restrict__ Bt,
                                                  const float* __restrict__ bq,
                                                  const float* __restrict__ bk,
                                                  const float* __restrict__ bv,
                                                  bf16* __restrict__ Out) {
    constexpr int K = DIM;
    __shared__ bf16 As[128 * 32];
    __shared__ bf16 Bs[128 * 32];
    int t = threadIdx.x;
    int l = t & 63;
    int w = t >> 6;
    int lr = l & 15, lg = l >> 4;
    int wr = w >> 1, wc = w & 1;
    int m0 = blockIdx.x * 128;
    int n0 = blockIdx.y * 128;

    f32x4_t acc[4][4] = {};

    int sr = t >> 2;           // staging row 0..63
    int sc = (t & 3) * 8;      // staging col chunk
    const bf16* ga = A + (size_t)(m0 + sr) * K + sc;
    const bf16* gb = Bt + (size_t)(n0 + sr) * K + sc;
    bf16* wa = As + t * 8;     // lane-ordered contiguous 16B slots
    bf16* wb = Bs + t * 8;

    for (int k0 = 0; k0 < K; k0 += 32) {
        gload_lds16(ga, wa);
        gload_lds16(ga + (size_t)64 * K, wa + 2048);
        gload_lds16(gb, wb);
        gload_lds16(gb + (size_t)64 * K, wb + 2048);
        ga += 32; gb += 32;
        __syncthreads();   // drains vmcnt -> LDS tiles ready
        bf16x8_t af[4], bfv[4];
#pragma unroll
        for (int mi = 0; mi < 4; ++mi)
            af[mi] = *(const bf16x8_t*)&As[(wr * 64 + mi * 16 + lr) * 32 + lg * 8];
#pragma unroll
        for (int ni = 0; ni < 4; ++ni)
            bfv[ni] = *(const bf16x8_t*)&Bs[(wc * 64 + ni * 16 + lr) * 32 + lg * 8];
#pragma unroll
        for (int mi = 0; mi < 4; ++mi)
#pragma unroll
            for (int ni = 0; ni < 4; ++ni)
                acc[mi][ni] = MFMA(af[mi], bfv[ni], acc[mi][ni]);
        __syncthreads();
    }

    int seg = n0 >> 10;  // 0=Q 1=K 2=V
    int nl = (n0 & 1023) + wc * 64;
    const float* bias = seg == 0 ? bq : seg == 1 ? bk : bv;
    // Q scale: 1/sqrt(hd) * log2(e), so attn softmax can use exp2 directly
    float alpha = seg == 0 ? 0.18033688011112042f : 1.0f;
    bf16* outp = Out + (size_t)seg * MROWS * DIM;
#pragma unroll
    for (int mi = 0; mi < 4; ++mi) {
#pragma unroll
        for (int ni = 0; ni < 4; ++ni) {
            int row = m0 + wr * 64 + mi * 16 + lg * 4;
            int col = nl + ni * 16 + lr;
            float bb = bias[col];
#pragma unroll
            for (int r = 0; r < 4; ++r) {
                float v = (acc[mi][ni][r] + bb) * alpha;
                outp[(size_t)(row + r) * DIM + col] = __float2bfloat16(v);
            }
        }
    }
}

// ------------- transpose V: (4096,1024) -> Vt (2,16,64,2048) -------------
__global__ __launch_bounds__(256) void k_transpose_v(const bf16* __restrict__ Vb,
                                                     bf16* __restrict__ Vt) {
    int s0 = blockIdx.x * 64;
    int bh = blockIdx.y;
    int b = bh >> 4, h = bh & 15;
    __shared__ bf16 tile[64][66];
    int t = threadIdx.x;
    int c = t & 63, rq = t >> 6;
#pragma unroll
    for (int j = 0; j < 16; ++j) {
        int s = rq + j * 4;
        tile[s][c] = Vb[(size_t)(b * SEQ + s0 + s) * DIM + h * HD + c];
    }
    __syncthreads();
#pragma unroll
    for (int j = 0; j < 16; ++j) {
        int d = rq + j * 4;
        Vt[((size_t)bh * HD + d) * SEQ + s0 + c] = tile[c][d];
    }
}

// ---- flash attention, swapped-operand form (one q-row per lane) ----
// 4 waves x 32 q-rows = 128 q/block; KVBLK=64; K/V staged via
// global_load_lds w16 double-buffered, XOR-swizzled rows.  mfma(K,Q)
// puts q on C-cols (lane-local): softmax = in-lane reduce + 2 shfls.
// Balanced 1D grid: block i<256 -> rank i (heavy), i>=256 -> rank 767-i
// (light, reversed) so co-resident pairs have ~constant total work.
// Both q-subtiles share ONE lgkmcnt(0) P-bounce wait; setprio around MFMA.
__global__ __launch_bounds__(256) void k_attn(const bf16* __restrict__ Qb,
                                              const bf16* __restrict__ Kb,
                                              const bf16* __restrict__ Vt,
                                              const int* __restrict__ amask,
                                              bf16* __restrict__ Ctx) {
    int i = blockIdx.x;
    int rank = (i < 256) ? i : 767 - i;
    int qt = 15 - (rank >> 5);         // heavy (long-span) ranks first
    int bh = rank & 31;
    int b = bh >> 4, h = bh & 15;
    int t = threadIdx.x;
    int w = t >> 6, l = t & 63;
    int lr = l & 15, lg = l >> 4;
    int m0 = qt * 128 + w * 32;        // wave's q-base (2 sub-tiles of 16)

    __shared__ bf16  Kl[2][64 * 64];   // [key][hd] swizzled, 8KB each
    __shared__ bf16  Vl[2][64 * 64];   // [hd][key] swizzled, 8KB each
    __shared__ float Bl[SEQ];          // additive key bias (0 / -1e30)
    __shared__ bf16  Ps[4][16 * 136];  // per-wave P scratch, both qi halves

    const bf16* vtb   = Vt + (size_t)bh * HD * SEQ;
    const bf16* kbase = Kb + (size_t)b * SEQ * DIM + h * HD;

    auto stage = [&](int kt, int bufi) {
#pragma unroll
        for (int c = 0; c < 2; ++c) {  // K tile 8KB: 256 thr x 16B x 2
            int P = t * 16 + c * 4096;
            int row = P >> 7;                       // key row 0..63
            int Lb = (P & 127) ^ ((row & 7) << 4);  // swizzled byte in row
            gload_lds16(kbase + (size_t)(kt * 64 + row) * DIM + (Lb >> 1),
                        (bf16*)((char*)&Kl[bufi][0] + P));
        }
#pragma unroll
        for (int c = 0; c < 2; ++c) {  // V^T tile 8KB (rows d, 128B each)
            int P = t * 16 + c * 4096;
            int row = P >> 7;
            int Lb = (P & 127) ^ ((row & 7) << 4);
            gload_lds16(vtb + (size_t)row * SEQ + kt * 64 + (Lb >> 1),
                        (bf16*)((char*)&Vl[bufi][0] + P));
        }
    };

    int nkt = 2 * qt + 2;              // kv tiles of 64 keys
    stage(0, 0);

    // padding-mask bias: one pass, 8 keys/thread
#pragma unroll
    for (int j = 0; j < 2; ++j) {
        int4 a4 = ((const int4*)(amask + b * SEQ))[t * 2 + j];
        int idx = (t * 2 + j) * 4;
        Bl[idx + 0] = a4.x > 0 ? 0.f : -1e30f;
        Bl[idx + 1] = a4.y > 0 ? 0.f : -1e30f;
        Bl[idx + 2] = a4.z > 0 ? 0.f : -1e30f;
        Bl[idx + 3] = a4.w > 0 ? 0.f : -1e30f;
    }

    // Q fragments (pre-scaled 0.125*log2e): 2 q-subtiles x 2 k-chunks
    const bf16* qbase = Qb + (size_t)(b * SEQ + m0 + lr) * DIM + h * HD;
    bf16x8_t qf[2][2];
#pragma unroll
    for (int qi = 0; qi < 2; ++qi)
#pragma unroll
        for (int ks = 0; ks < 2; ++ks)
            qf[qi][ks] = *(const bf16x8_t*)(qbase + (size_t)qi * 16 * DIM + ks * 32 + lg * 8);

    f32x4_t o[2][4] = {};
    float mrow[2] = {-1e30f, -1e30f}, lrow[2] = {0.f, 0.f};
    bf16* ps = &Ps[w][0];

    __syncthreads();                   // K[0],V[0],Bl ready
    int buf = 0;
    for (int kt = 0; kt < nkt; ++kt) {
        if (kt + 1 < nkt) stage(kt + 1, buf ^ 1);   // async prefetch
        const char* Klb = (const char*)&Kl[buf][0];
        const char* Vlb = (const char*)&Vl[buf][0];

        // ---- K fragments (shared across both q-subtiles) ----
        bf16x8_t kf[4][2];
#pragma unroll
        for (int ni = 0; ni < 4; ++ni) {
            int row = ni * 16 + lr;
#pragma unroll
            for (int ks = 0; ks < 2; ++ks)
                kf[ni][ks] = *(const bf16x8_t*)(Klb + row * 128 +
                                 ((ks * 64 + lg * 16) ^ ((row & 7) << 4)));
        }
        // ---- V^T fragments (shared across q-subtiles) ----
        bf16x8_t vf[4][2];
#pragma unroll
        for (int ni = 0; ni < 4; ++ni) {
            int row = ni * 16 + lr;
#pragma unroll
            for (int kc = 0; kc < 2; ++kc)
                vf[ni][kc] = *(const bf16x8_t*)(Vlb + row * 128 +
                                 ((kc * 64 + lg * 16) ^ ((row & 7) << 4)));
        }
        // ---- bias (key-only, shared across q) ----
        f32x4_t b4[4];
#pragma unroll
        for (int ni = 0; ni < 4; ++ni)
            b4[ni] = *(const f32x4_t*)&Bl[kt * 64 + ni * 16 + lg * 4];

        // ---- scores for BOTH q-subtiles: mfma(K,Q) -> C[key][q] ----
        f32x4_t s[2][4];
        __builtin_amdgcn_s_setprio(1);
#pragma unroll
        for (int qi = 0; qi < 2; ++qi)
#pragma unroll
            for (int ni = 0; ni < 4; ++ni) {
                f32x4_t a = {0.f, 0.f, 0.f, 0.f};
                a = MFMA(kf[ni][0], qf[qi][0], a);
                a = MFMA(kf[ni][1], qf[qi][1], a);
                s[qi][ni] = a + b4[ni];    // additive padding mask
            }
        __builtin_amdgcn_s_setprio(0);

        // ---- mask + online softmax + P-write, per qi ----
        asm volatile("" ::: "memory");
#pragma unroll
        for (int qi = 0; qi < 2; ++qi) {
            int q = m0 + qi * 16 + lr;
            if (kt * 64 + 63 > m0 + qi * 16) {   // causal mask
#pragma unroll
                for (int ni = 0; ni < 4; ++ni)
#pragma unroll
                    for (int r = 0; r < 4; ++r) {
                        int key = kt * 64 + ni * 16 + lg * 4 + r;
                        if (key > q) s[qi][ni][r] = -1e30f;
                    }
            }
            float tm = fmaxf(
                fmaxf(fmaxf(fmaxf(s[qi][0][0], s[qi][0][1]), fmaxf(s[qi][0][2], s[qi][0][3])),
                      fmaxf(fmaxf(s[qi][1][0], s[qi][1][1]), fmaxf(s[qi][1][2], s[qi][1][3]))),
                fmaxf(fmaxf(fmaxf(s[qi][2][0], s[qi][2][1]), fmaxf(s[qi][2][2], s[qi][2][3])),
                      fmaxf(fmaxf(s[qi][3][0], s[qi][3][1]), fmaxf(s[qi][3][2], s[qi][3][3]))));
            tm = fmaxf(tm, __shfl_xor(tm, 16));
            tm = fmaxf(tm, __shfl_xor(tm, 32));
            float mnew = fmaxf(mrow[qi], tm);
            float al = fexp2(mrow[qi] - mnew);
            mrow[qi] = mnew;
            float rs = 0.f;
#pragma unroll
            for (int ni = 0; ni < 4; ++ni) {
#pragma unroll
                for (int r = 0; r < 4; ++r) {
                    float p = fexp2(s[qi][ni][r] - mnew);
                    s[qi][ni][r] = p;
                    rs += p;
                }
            }
            rs += __shfl_xor(rs, 16);
            rs += __shfl_xor(rs, 32);
            lrow[qi] = lrow[qi] * al + rs;
#pragma unroll
            for (int ni = 0; ni < 4; ++ni)
                o[qi][ni] *= al;
#pragma unroll
            for (int ni = 0; ni < 4; ++ni)
                *(ushort4*)&ps[lr * 136 + qi * 64 + ni * 16 + lg * 4] = pack4(s[qi][ni]);
        }
        // single per-wave fence for both qi halves
        asm volatile("s_waitcnt lgkmcnt(0)" ::: "memory");
        __builtin_amdgcn_sched_barrier(0);

        // ---- PV for both qi: mfma(V^T, P) -> O^T[d][q] ----
        __builtin_amdgcn_s_setprio(1);
#pragma unroll
        for (int qi = 0; qi < 2; ++qi) {
            bf16x8_t pf[2];
#pragma unroll
            for (int kc = 0; kc < 2; ++kc)
                pf[kc] = *(const bf16x8_t*)&ps[lr * 136 + qi * 64 + kc * 32 + lg * 8];
#pragma unroll
            for (int ni = 0; ni < 4; ++ni) {
                o[qi][ni] = MFMA(vf[ni][0], pf[0], o[qi][ni]);
                o[qi][ni] = MFMA(vf[ni][1], pf[1], o[qi][ni]);
            }
        }
        __builtin_amdgcn_s_setprio(0);
        __syncthreads();               // drain prefetch + buffer handoff
        buf ^= 1;
    }

    // ---- normalize and write ctx: lane q = m0+qi*16+lr, d = ni*16+lg*4+r ----
#pragma unroll
    for (int qi = 0; qi < 2; ++qi) {
        float inv = 1.0f / lrow[qi];
        size_t row = (size_t)(b * SEQ + m0 + qi * 16 + lr);
#pragma unroll
        for (int ni = 0; ni < 4; ++ni) {
            f32x4_t v = o[qi][ni];
            v *= inv;
            *(ushort4*)&Ctx[row * DIM + h * HD + ni * 16 + lg * 4] = pack4(v);
        }
    }
}

// ---------------- output projection GEMM -> fp32 d_out ----------------
__global__ __launch_bounds__(256) void k_gemm_out(const bf16* __restrict__ A,
                                                  const bf16* __restrict__ Bt,
                                                  const float* __restrict__ bias,
                                                  float* __restrict__ Out) {
    constexpr int K = DIM;
    __shared__ bf16 As[128 * 32];
    __shared__ bf16 Bs[128 * 32];
    int t = threadIdx.x;
    int l = t & 63;
    int w = t >> 6;
    int lr = l & 15, lg = l >> 4;
    int wr = w >> 1, wc = w & 1;
    int m0 = blockIdx.x * 128;
    int n0 = blockIdx.y * 128;

    f32x4_t acc[4][4] = {};

    int sr = t >> 2;
    int sc = (t & 3) * 8;
    const bf16* ga = A + (size_t)(m0 + sr) * K + sc;
    const bf16* gb = Bt + (size_t)(n0 + sr) * K + sc;
    bf16* wa = As + t * 8;
    bf16* wb = Bs + t * 8;

    for (int k0 = 0; k0 < K; k0 += 32) {
        gload_lds16(ga, wa);
        gload_lds16(ga + (size_t)64 * K, wa + 2048);
        gload_lds16(gb, wb);
        gload_lds16(gb + (size_t)64 * K, wb + 2048);
        ga += 32; gb += 32;
        __syncthreads();
        bf16x8_t af[4], bfv[4];
#pragma unroll
        for (int mi = 0; mi < 4; ++mi)
            af[mi] = *(const bf16x8_t*)&As[(wr * 64 + mi * 16 + lr) * 32 + lg * 8];
#pragma unroll
        for (int ni = 0; ni < 4; ++ni)
            bfv[ni] = *(const bf16x8_t*)&Bs[(wc * 64 + ni * 16 + lr) * 32 + lg * 8];
#pragma unroll
        for (int mi = 0; mi < 4; ++mi)
#pragma unroll
            for (int ni = 0; ni < 4; ++ni)
                acc[mi][ni] = MFMA(af[mi], bfv[ni], acc[mi][ni]);
        __syncthreads();
    }

    int nl = n0 + wc * 64;
#pragma unroll
    for (int mi = 0; mi < 4; ++mi) {
#pragma unroll
        for (int ni = 0; ni < 4; ++ni) {
            int row = m0 + wr * 64 + mi * 16 + lg * 4;
            int col = nl + ni * 16 + lr;
            float bb = bias[col];
#pragma unroll
            for (int r = 0; r < 4; ++r)
                Out[(size_t)(row + r) * DIM + col] = acc[mi][ni][r] + bb;
        }
    }
}

extern "C" void kernel_launch(void* const* d_in, const int* in_sizes, int n_in,
                              void* d_out, int out_size, void* d_ws, size_t ws_size,
                              hipStream_t stream) {
    const float* x  = (const float*)d_in[0];
    const int*   am = (const int*)d_in[1];
    const float* Wq = (const float*)d_in[2];
    const float* bq = (const float*)d_in[3];
    const float* Wk = (const float*)d_in[4];
    const float* bk = (const float*)d_in[5];
    const float* Wv = (const float*)d_in[6];
    const float* bv = (const float*)d_in[7];
    const float* Wo = (const float*)d_in[8];
    const float* bo = (const float*)d_in[9];

    char* ws = (char*)d_ws;
    const size_t MB = (size_t)1 << 20;
    bf16* xb  = (bf16*)(ws + 0 * MB);
    bf16* Wt  = (bf16*)(ws + 8 * MB);
    bf16* Qb  = (bf16*)(ws + 16 * MB);   // Q|K|V contiguous (24 MB)
    bf16* Vb  = (bf16*)(ws + 32 * MB);
    bf16* Vt  = (bf16*)(ws + 40 * MB);
    bf16* Ctx = (bf16*)(ws + 48 * MB);

    k_convert_x<<<dim3(MROWS * DIM / 4 / 256), 256, 0, stream>>>(
        (const float4*)x, (ushort4*)xb);
    k_transpose_w<<<dim3(16, 16, 4), 256, 0, stream>>>(Wq, Wk, Wv, Wo, Wt);
    k_gemm_qkv<<<dim3(32, 24), 256, 0, stream>>>(xb, Wt, bq, bk, bv, Qb);
    k_transpose_v<<<dim3(32, 32), 256, 0, stream>>>(Vb, Vt);
    k_attn<<<dim3(512), 256, 0, stream>>>(Qb, Qb + (size_t)MROWS * DIM, Vt, am, Ctx);
    k_gemm_out<<<dim3(32, 8), 256, 0, stream>>>(Ctx, Wt + (size_t)3 * DIM * DIM, bo,
                                                (float*)d_out);
}

// Round 7
// 193.075 us; speedup vs baseline: 2.1037x; 1.1206x over previous
//
#include <hip/hip_runtime.h>
#include <hip/hip_bf16.h>

// MultiHeadSelfAttention on MI355X (gfx950), bf16 MFMA pipeline.
// Workspace layout (needs 56 MB):
//   [ 0MB) xb   : x as bf16            (4096x1024)
//   [ 8MB) Wt   : Wq^T|Wk^T|Wv^T|Wo^T  (4 x 1024x1024 bf16)
//   [16MB) Qb   : Q (pre-scaled 0.125*log2e) (4096x1024 bf16)
//   [24MB) Kb   : K                    (4096x1024 bf16)
//   [32MB) Vb   : V                    (4096x1024 bf16)
//   [40MB) Vt   : V^T per head         (2,16,64,2048 bf16)
//   [48MB) Ctx  : attention output     (4096x1024 bf16)

using bf16 = __hip_bfloat16;
typedef __attribute__((ext_vector_type(8))) short bf16x8_t;
typedef __attribute__((ext_vector_type(4))) float f32x4_t;

#define MFMA(a, b, c) __builtin_amdgcn_mfma_f32_16x16x32_bf16((a), (b), (c), 0, 0, 0)

constexpr int SEQ = 2048;
constexpr int DIM = 1024;
constexpr int HD  = 64;
constexpr int MROWS = 2 * SEQ;  // 4096

// async global->LDS, 16B per lane (m97 pattern). LDS dest must be
// wave-uniform base + lane*16 in lane order (m104) — our layouts are.
__device__ __forceinline__ void gload_lds16(const bf16* g, bf16* l) {
    __builtin_amdgcn_global_load_lds(
        (const __attribute__((address_space(1))) unsigned int*)g,
        (__attribute__((address_space(3))) unsigned int*)l, 16, 0, 0);
}

__device__ __forceinline__ ushort4 pack4(f32x4_t v) {
    ushort4 u;
    u.x = __builtin_bit_cast(unsigned short, __float2bfloat16(v[0]));
    u.y = __builtin_bit_cast(unsigned short, __float2bfloat16(v[1]));
    u.z = __builtin_bit_cast(unsigned short, __float2bfloat16(v[2]));
    u.w = __builtin_bit_cast(unsigned short, __float2bfloat16(v[3]));
    return u;
}

// exp2 fast path (Q is pre-scaled by log2e so softmax uses raw v_exp_f32)
__device__ __forceinline__ float fexp2(float x) {
#if __has_builtin(__builtin_amdgcn_exp2f)
    return __builtin_amdgcn_exp2f(x);
#else
    return exp2f(x);
#endif
}

// ---------------- convert x: fp32 -> bf16, 4 elems/thread ----------------
__global__ __launch_bounds__(256) void k_convert_x(const float4* __restrict__ x,
                                                   ushort4* __restrict__ xb) {
    int i = blockIdx.x * 256 + threadIdx.x;
    float4 v = x[i];
    ushort4 o;
    o.x = __builtin_bit_cast(unsigned short, __float2bfloat16(v.x));
    o.y = __builtin_bit_cast(unsigned short, __float2bfloat16(v.y));
    o.z = __builtin_bit_cast(unsigned short, __float2bfloat16(v.z));
    o.w = __builtin_bit_cast(unsigned short, __float2bfloat16(v.w));
    xb[i] = o;
}

// -------- transpose+convert weights: W (k,n) fp32 -> Wt (n,k) bf16 --------
__global__ __launch_bounds__(256) void k_transpose_w(const float* __restrict__ W0,
                                                     const float* __restrict__ W1,
                                                     const float* __restrict__ W2,
                                                     const float* __restrict__ W3,
                                                     bf16* __restrict__ Wt) {
    const float* W = blockIdx.z == 0 ? W0 : blockIdx.z == 1 ? W1
                   : blockIdx.z == 2 ? W2 : W3;
    bf16* out = Wt + (size_t)blockIdx.z * DIM * DIM;
    __shared__ float tile[64][65];
    int r0 = blockIdx.x * 64, c0 = blockIdx.y * 64;
    int t = threadIdx.x;
    int c = t & 63, rq = t >> 6;
#pragma unroll
    for (int j = 0; j < 16; ++j) {
        int r = rq + j * 4;
        tile[r][c] = W[(size_t)(r0 + r) * DIM + c0 + c];
    }
    __syncthreads();
#pragma unroll
    for (int j = 0; j < 16; ++j) {
        int n = rq + j * 4;
        out[(size_t)(c0 + n) * DIM + r0 + c] = __float2bfloat16(tile[c][n]);
    }
}

// ------- fused QKV GEMM: 128x128 tile, 4 waves, dbuf prefetch (m97) -------
// A (4096,1024) bf16; Bt = Wq^T|Wk^T|Wv^T (3072,1024); Out = Q|K|V contiguous.
__global__ __launch_bounds__(256) void k_gemm_qkv(const bf16* __restrict__ A,
                                                  const bf16* __restrict__ Bt,
                                                  const float* __restrict__ bq,
                                                  const float* __restrict__ bk,
                                                  const float* __restrict__ bv,
                                                  bf16* __restrict__ Out) {
    constexpr int K = DIM;
    __shared__ bf16 As[2][128 * 32];
    __shared__ bf16 Bs[2][128 * 32];
    int t = threadIdx.x;
    int l = t & 63;
    int w = t >> 6;
    int lr = l & 15, lg = l >> 4;
    int wr = w >> 1, wc = w & 1;
    int m0 = blockIdx.x * 128;
    int n0 = blockIdx.y * 128;

    f32x4_t acc[4][4] = {};

    int sr = t >> 2;           // staging row 0..63
    int sc = (t & 3) * 8;      // staging col chunk
    const bf16* ga = A + (size_t)(m0 + sr) * K + sc;
    const bf16* gb = Bt + (size_t)(n0 + sr) * K + sc;

    auto stage = [&](int k0, int bi) {
        gload_lds16(ga + k0, &As[bi][t * 8]);
        gload_lds16(ga + k0 + (size_t)64 * K, &As[bi][t * 8 + 2048]);
        gload_lds16(gb + k0, &Bs[bi][t * 8]);
        gload_lds16(gb + k0 + (size_t)64 * K, &Bs[bi][t * 8 + 2048]);
    };

    stage(0, 0);
    __syncthreads();           // drain: tile 0 ready
    int buf = 0;
    for (int k0 = 0; k0 < K; k0 += 32) {
        if (k0 + 32 < K) stage(k0 + 32, buf ^ 1);   // prefetch next tile
        bf16x8_t af[4], bfv[4];
#pragma unroll
        for (int mi = 0; mi < 4; ++mi)
            af[mi] = *(const bf16x8_t*)&As[buf][(wr * 64 + mi * 16 + lr) * 32 + lg * 8];
#pragma unroll
        for (int ni = 0; ni < 4; ++ni)
            bfv[ni] = *(const bf16x8_t*)&Bs[buf][(wc * 64 + ni * 16 + lr) * 32 + lg * 8];
#pragma unroll
        for (int mi = 0; mi < 4; ++mi)
#pragma unroll
            for (int ni = 0; ni < 4; ++ni)
                acc[mi][ni] = MFMA(af[mi], bfv[ni], acc[mi][ni]);
        __syncthreads();       // drains prefetch; next tile ready
        buf ^= 1;
    }

    int seg = n0 >> 10;  // 0=Q 1=K 2=V
    int nl = (n0 & 1023) + wc * 64;
    const float* bias = seg == 0 ? bq : seg == 1 ? bk : bv;
    // Q scale: 1/sqrt(hd) * log2(e), so attn softmax can use exp2 directly
    float alpha = seg == 0 ? 0.18033688011112042f : 1.0f;
    bf16* outp = Out + (size_t)seg * MROWS * DIM;
#pragma unroll
    for (int mi = 0; mi < 4; ++mi) {
#pragma unroll
        for (int ni = 0; ni < 4; ++ni) {
            int row = m0 + wr * 64 + mi * 16 + lg * 4;
            int col = nl + ni * 16 + lr;
            float bb = bias[col];
#pragma unroll
            for (int r = 0; r < 4; ++r) {
                float v = (acc[mi][ni][r] + bb) * alpha;
                outp[(size_t)(row + r) * DIM + col] = __float2bfloat16(v);
            }
        }
    }
}

// ------------- transpose V: (4096,1024) -> Vt (2,16,64,2048) -------------
__global__ __launch_bounds__(256) void k_transpose_v(const bf16* __restrict__ Vb,
                                                     bf16* __restrict__ Vt) {
    int s0 = blockIdx.x * 64;
    int bh = blockIdx.y;
    int b = bh >> 4, h = bh & 15;
    __shared__ bf16 tile[64][66];
    int t = threadIdx.x;
    int c = t & 63, rq = t >> 6;
#pragma unroll
    for (int j = 0; j < 16; ++j) {
        int s = rq + j * 4;
        tile[s][c] = Vb[(size_t)(b * SEQ + s0 + s) * DIM + h * HD + c];
    }
    __syncthreads();
#pragma unroll
    for (int j = 0; j < 16; ++j) {
        int d = rq + j * 4;
        Vt[((size_t)bh * HD + d) * SEQ + s0 + c] = tile[c][d];
    }
}

// ---- flash attention, swapped-operand form (one q-row per lane) ----
// 4 waves x 16 q-rows = 64 q/block; KVBLK=64; 1024 blocks heavy-first
// (LPT backfill at 3 blocks/CU).  K/V staged via global_load_lds w16,
// double-buffered, XOR-swizzled rows.  mfma(K,Q) puts q on C-cols
// (lane-local): softmax = in-lane reduce + 2 shfls.  Padding mask staged
// once as additive f32 bias in LDS.
__global__ __launch_bounds__(256) void k_attn(const bf16* __restrict__ Qb,
                                              const bf16* __restrict__ Kb,
                                              const bf16* __restrict__ Vt,
                                              const int* __restrict__ amask,
                                              bf16* __restrict__ Ctx) {
    int rank = blockIdx.x;
    int qt = 31 - (rank >> 5);         // heavy (long-span) blocks first
    int bh = rank & 31;
    int b = bh >> 4, h = bh & 15;
    int t = threadIdx.x;
    int w = t >> 6, l = t & 63;
    int lr = l & 15, lg = l >> 4;
    int m0 = qt * 64 + w * 16;         // this wave's 16 q-rows

    __shared__ bf16  Kl[2][64 * 64];   // [key][hd] swizzled, 8KB each
    __shared__ bf16  Vl[2][64 * 64];   // [hd][key] swizzled, 8KB each
    __shared__ float Bl[SEQ];          // additive key bias (0 / -1e30)
    __shared__ bf16  Ps[4][16 * 72];   // per-wave P scratch

    const bf16* vtb   = Vt + (size_t)bh * HD * SEQ;
    const bf16* kbase = Kb + (size_t)b * SEQ * DIM + h * HD;

    auto stage = [&](int kt, int bufi) {
#pragma unroll
        for (int c = 0; c < 2; ++c) {  // K tile 8KB: 256 thr x 16B x 2
            int P = t * 16 + c * 4096;
            int row = P >> 7;                       // key row 0..63
            int Lb = (P & 127) ^ ((row & 7) << 4);  // swizzled byte in row
            gload_lds16(kbase + (size_t)(kt * 64 + row) * DIM + (Lb >> 1),
                        (bf16*)((char*)&Kl[bufi][0] + P));
        }
#pragma unroll
        for (int c = 0; c < 2; ++c) {  // V^T tile 8KB (rows d, 128B each)
            int P = t * 16 + c * 4096;
            int row = P >> 7;
            int Lb = (P & 127) ^ ((row & 7) << 4);
            gload_lds16(vtb + (size_t)row * SEQ + kt * 64 + (Lb >> 1),
                        (bf16*)((char*)&Vl[bufi][0] + P));
        }
    };

    int nkt = qt + 1;                  // kv tiles of 64 keys
    stage(0, 0);

    // padding-mask bias: one pass, 8 keys/thread
#pragma unroll
    for (int j = 0; j < 2; ++j) {
        int4 a4 = ((const int4*)(amask + b * SEQ))[t * 2 + j];
        int idx = (t * 2 + j) * 4;
        Bl[idx + 0] = a4.x > 0 ? 0.f : -1e30f;
        Bl[idx + 1] = a4.y > 0 ? 0.f : -1e30f;
        Bl[idx + 2] = a4.z > 0 ? 0.f : -1e30f;
        Bl[idx + 3] = a4.w > 0 ? 0.f : -1e30f;
    }

    // Q fragments (pre-scaled 0.125*log2e)
    const bf16* qbase = Qb + (size_t)(b * SEQ + m0 + lr) * DIM + h * HD;
    bf16x8_t qf[2];
#pragma unroll
    for (int ks = 0; ks < 2; ++ks)
        qf[ks] = *(const bf16x8_t*)(qbase + ks * 32 + lg * 8);

    f32x4_t o[4] = {};
    float mrow = -1e30f, lrow = 0.f;
    bf16* ps = &Ps[w][0];

    __syncthreads();                   // K[0],V[0],Bl ready
    int buf = 0;
    for (int kt = 0; kt < nkt; ++kt) {
        if (kt + 1 < nkt) stage(kt + 1, buf ^ 1);   // async prefetch
        const char* Klb = (const char*)&Kl[buf][0];
        const char* Vlb = (const char*)&Vl[buf][0];

        // ---- K / V^T fragments ----
        bf16x8_t kf[4][2], vf[4][2];
#pragma unroll
        for (int ni = 0; ni < 4; ++ni) {
            int row = ni * 16 + lr;
#pragma unroll
            for (int ks = 0; ks < 2; ++ks) {
                kf[ni][ks] = *(const bf16x8_t*)(Klb + row * 128 +
                                 ((ks * 64 + lg * 16) ^ ((row & 7) << 4)));
                vf[ni][ks] = *(const bf16x8_t*)(Vlb + row * 128 +
                                 ((ks * 64 + lg * 16) ^ ((row & 7) << 4)));
            }
        }
        // ---- bias (key-only) ----
        f32x4_t b4[4];
#pragma unroll
        for (int ni = 0; ni < 4; ++ni)
            b4[ni] = *(const f32x4_t*)&Bl[kt * 64 + ni * 16 + lg * 4];

        // ---- scores: mfma(K,Q) -> C[key][q], q lane-local (lr) ----
        f32x4_t s[4];
        __builtin_amdgcn_s_setprio(1);
#pragma unroll
        for (int ni = 0; ni < 4; ++ni) {
            f32x4_t a = {0.f, 0.f, 0.f, 0.f};
            a = MFMA(kf[ni][0], qf[0], a);
            a = MFMA(kf[ni][1], qf[1], a);
            s[ni] = a + b4[ni];        // additive padding mask
        }
        __builtin_amdgcn_s_setprio(0);

        // ---- causal mask (only the diagonal tile needs it) ----
        int q = m0 + lr;
        if (kt * 64 + 63 > m0) {
#pragma unroll
            for (int ni = 0; ni < 4; ++ni)
#pragma unroll
                for (int r = 0; r < 4; ++r) {
                    int key = kt * 64 + ni * 16 + lg * 4 + r;
                    if (key > q) s[ni][r] = -1e30f;
                }
        }
        // ---- online softmax: 15 in-lane + 2 shfls ----
        float tm = fmaxf(
            fmaxf(fmaxf(fmaxf(s[0][0], s[0][1]), fmaxf(s[0][2], s[0][3])),
                  fmaxf(fmaxf(s[1][0], s[1][1]), fmaxf(s[1][2], s[1][3]))),
            fmaxf(fmaxf(fmaxf(s[2][0], s[2][1]), fmaxf(s[2][2], s[2][3])),
                  fmaxf(fmaxf(s[3][0], s[3][1]), fmaxf(s[3][2], s[3][3]))));
        tm = fmaxf(tm, __shfl_xor(tm, 16));
        tm = fmaxf(tm, __shfl_xor(tm, 32));
        float mnew = fmaxf(mrow, tm);
        float al = fexp2(mrow - mnew);
        mrow = mnew;
        float rs = 0.f;
#pragma unroll
        for (int ni = 0; ni < 4; ++ni) {
#pragma unroll
            for (int r = 0; r < 4; ++r) {
                float p = fexp2(s[ni][r] - mnew);
                s[ni][r] = p;
                rs += p;
            }
        }
        rs += __shfl_xor(rs, 16);
        rs += __shfl_xor(rs, 32);
        lrow = lrow * al + rs;
#pragma unroll
        for (int ni = 0; ni < 4; ++ni)
            o[ni] *= al;
        // ---- P -> per-wave LDS -> B-fragments ----
        asm volatile("" ::: "memory");
#pragma unroll
        for (int ni = 0; ni < 4; ++ni)
            *(ushort4*)&ps[lr * 72 + ni * 16 + lg * 4] = pack4(s[ni]);
        asm volatile("s_waitcnt lgkmcnt(0)" ::: "memory");
        __builtin_amdgcn_sched_barrier(0);
        bf16x8_t pf[2];
#pragma unroll
        for (int kc = 0; kc < 2; ++kc)
            pf[kc] = *(const bf16x8_t*)&ps[lr * 72 + kc * 32 + lg * 8];
        // ---- PV: mfma(V^T, P) -> O^T[d][q] ----
        __builtin_amdgcn_s_setprio(1);
#pragma unroll
        for (int ni = 0; ni < 4; ++ni) {
            o[ni] = MFMA(vf[ni][0], pf[0], o[ni]);
            o[ni] = MFMA(vf[ni][1], pf[1], o[ni]);
        }
        __builtin_amdgcn_s_setprio(0);
        __syncthreads();               // drain prefetch + buffer handoff
        buf ^= 1;
    }

    // ---- normalize and write ctx: lane q = m0+lr, d = ni*16+lg*4+r ----
    float inv = 1.0f / lrow;
    size_t row = (size_t)(b * SEQ + m0 + lr);
#pragma unroll
    for (int ni = 0; ni < 4; ++ni) {
        f32x4_t v = o[ni];
        v *= inv;
        *(ushort4*)&Ctx[row * DIM + h * HD + ni * 16 + lg * 4] = pack4(v);
    }
}

// ------- output projection GEMM -> fp32 d_out, dbuf prefetch (m97) -------
__global__ __launch_bounds__(256) void k_gemm_out(const bf16* __restrict__ A,
                                                  const bf16* __restrict__ Bt,
                                                  const float* __restrict__ bias,
                                                  float* __restrict__ Out) {
    constexpr int K = DIM;
    __shared__ bf16 As[2][128 * 32];
    __shared__ bf16 Bs[2][128 * 32];
    int t = threadIdx.x;
    int l = t & 63;
    int w = t >> 6;
    int lr = l & 15, lg = l >> 4;
    int wr = w >> 1, wc = w & 1;
    int m0 = blockIdx.x * 128;
    int n0 = blockIdx.y * 128;

    f32x4_t acc[4][4] = {};

    int sr = t >> 2;
    int sc = (t & 3) * 8;
    const bf16* ga = A + (size_t)(m0 + sr) * K + sc;
    const bf16* gb = Bt + (size_t)(n0 + sr) * K + sc;

    auto stage = [&](int k0, int bi) {
        gload_lds16(ga + k0, &As[bi][t * 8]);
        gload_lds16(ga + k0 + (size_t)64 * K, &As[bi][t * 8 + 2048]);
        gload_lds16(gb + k0, &Bs[bi][t * 8]);
        gload_lds16(gb + k0 + (size_t)64 * K, &Bs[bi][t * 8 + 2048]);
    };

    stage(0, 0);
    __syncthreads();
    int buf = 0;
    for (int k0 = 0; k0 < K; k0 += 32) {
        if (k0 + 32 < K) stage(k0 + 32, buf ^ 1);
        bf16x8_t af[4], bfv[4];
#pragma unroll
        for (int mi = 0; mi < 4; ++mi)
            af[mi] = *(const bf16x8_t*)&As[buf][(wr * 64 + mi * 16 + lr) * 32 + lg * 8];
#pragma unroll
        for (int ni = 0; ni < 4; ++ni)
            bfv[ni] = *(const bf16x8_t*)&Bs[buf][(wc * 64 + ni * 16 + lr) * 32 + lg * 8];
#pragma unroll
        for (int mi = 0; mi < 4; ++mi)
#pragma unroll
            for (int ni = 0; ni < 4; ++ni)
                acc[mi][ni] = MFMA(af[mi], bfv[ni], acc[mi][ni]);
        __syncthreads();
        buf ^= 1;
    }

    int nl = n0 + wc * 64;
#pragma unroll
    for (int mi = 0; mi < 4; ++mi) {
#pragma unroll
        for (int ni = 0; ni < 4; ++ni) {
            int row = m0 + wr * 64 + mi * 16 + lg * 4;
            int col = nl + ni * 16 + lr;
            float bb = bias[col];
#pragma unroll
            for (int r = 0; r < 4; ++r)
                Out[(size_t)(row + r) * DIM + col] = acc[mi][ni][r] + bb;
        }
    }
}

extern "C" void kernel_launch(void* const* d_in, const int* in_sizes, int n_in,
                              void* d_out, int out_size, void* d_ws, size_t ws_size,
                              hipStream_t stream) {
    const float* x  = (const float*)d_in[0];
    const int*   am = (const int*)d_in[1];
    const float* Wq = (const float*)d_in[2];
    const float* bq = (const float*)d_in[3];
    const float* Wk = (const float*)d_in[4];
    const float* bk = (const float*)d_in[5];
    const float* Wv = (const float*)d_in[6];
    const float* bv = (const float*)d_in[7];
    const float* Wo = (const float*)d_in[8];
    const float* bo = (const float*)d_in[9];

    char* ws = (char*)d_ws;
    const size_t MB = (size_t)1 << 20;
    bf16* xb  = (bf16*)(ws + 0 * MB);
    bf16* Wt  = (bf16*)(ws + 8 * MB);
    bf16* Qb  = (bf16*)(ws + 16 * MB);   // Q|K|V contiguous (24 MB)
    bf16* Vb  = (bf16*)(ws + 32 * MB);
    bf16* Vt  = (bf16*)(ws + 40 * MB);
    bf16* Ctx = (bf16*)(ws + 48 * MB);

    k_convert_x<<<dim3(MROWS * DIM / 4 / 256), 256, 0, stream>>>(
        (const float4*)x, (ushort4*)xb);
    k_transpose_w<<<dim3(16, 16, 4), 256, 0, stream>>>(Wq, Wk, Wv, Wo, Wt);
    k_gemm_qkv<<<dim3(32, 24), 256, 0, stream>>>(xb, Wt, bq, bk, bv, Qb);
    k_transpose_v<<<dim3(32, 32), 256, 0, stream>>>(Vb, Vt);
    k_attn<<<dim3(1024), 256, 0, stream>>>(Qb, Qb + (size_t)MROWS * DIM, Vt, am, Ctx);
    k_gemm_out<<<dim3(32, 8), 256, 0, stream>>>(Ctx, Wt + (size_t)3 * DIM * DIM, bo,
                                                (float*)d_out);
}